// Round 1
// baseline (229.426 us; speedup 1.0000x reference)
//
#include <hip/hip_runtime.h>

// ---------------------------------------------------------------------------
// LargeWindowAttention on MI355X (gfx950)
// Pipeline: pool -> ctx(LN+mix) / q relayout -> QKV GEMMs (bf16 MFMA) ->
//           batched window attention -> out GEMM -> image relayout.
// All matmuls: mfma_f32_16x16x32_bf16, fp32 accum. Softmax/LN stats fp32.
// Workspace budget ~94.4 MB (aliased by lifetime).
// ---------------------------------------------------------------------------

typedef __bf16 bf16;
typedef __bf16 bf16x2 __attribute__((ext_vector_type(2)));
typedef __bf16 bf16x4 __attribute__((ext_vector_type(4)));
typedef __bf16 bf16x8 __attribute__((ext_vector_type(8)));
typedef float f32x4 __attribute__((ext_vector_type(4)));

#define MFMA(a, b, c) __builtin_amdgcn_mfma_f32_16x16x32_bf16(a, b, c, 0, 0, 0)

__device__ __forceinline__ void gll16(const void* g, void* l) {
  __builtin_amdgcn_global_load_lds((const __attribute__((address_space(1))) void*)g,
                                   (__attribute__((address_space(3))) void*)l, 16, 0, 0);
}

// ---------------------------------------------------------------------------
// Convert in_w (1536x512) and out_w (512x512) fp32 -> bf16
__global__ void k_wconv(const float* __restrict__ in_w, const float* __restrict__ out_w,
                        bf16* __restrict__ wib, bf16* __restrict__ wob) {
  int i = blockIdx.x * blockDim.x + threadIdx.x;  // 0..262143
  const int n1 = (1536 * 512) / 4;
  float4 v;
  bf16* dst;
  if (i < n1) { v = ((const float4*)in_w)[i];      dst = wib + (size_t)i * 4; }
  else        { v = ((const float4*)out_w)[i - n1]; dst = wob + (size_t)(i - n1) * 4; }
  dst[0] = (bf16)v.x; dst[1] = (bf16)v.y; dst[2] = (bf16)v.z; dst[3] = (bf16)v.w;
}

// ---------------------------------------------------------------------------
// 2x2 average pool of x[512][128][128] -> xp2t[y2][x2][c]  (c-contiguous)
__global__ void k_pool(const float* __restrict__ x, float* __restrict__ xp2t) {
  __shared__ float pooled[128][65];
  const int y2 = blockIdx.x, c0 = blockIdx.y * 128, t = threadIdx.x;
  #pragma unroll
  for (int i = 0; i < 32; ++i) {
    int flat = i * 256 + t;            // 128 c x 64 x2
    int ci = flat >> 6, x2 = flat & 63;
    const float* p = x + (size_t)(c0 + ci) * 16384 + (size_t)(2 * y2) * 128 + 2 * x2;
    float2 a = *(const float2*)p;
    float2 b = *(const float2*)(p + 128);
    pooled[ci][x2] = 0.25f * (a.x + a.y + b.x + b.y);
  }
  __syncthreads();
  #pragma unroll
  for (int j = 0; j < 32; ++j) {
    int flat = j * 256 + t;            // 64 x2 x 128 c
    int x2 = flat >> 7, ci = flat & 127;
    xp2t[(size_t)(y2 * 64 + x2) * 512 + c0 + ci] = pooled[ci][x2];
  }
}

// ---------------------------------------------------------------------------
// q relayout: x[c][Y][X] -> q_bf16[(l*256+s)*512 + c], l=py*8+px, s=hy*16+hx
__global__ void k_qprep(const float* __restrict__ x, bf16* __restrict__ q) {
  __shared__ float xs[64][129];
  const int hy = blockIdx.x, py = blockIdx.y, c0 = blockIdx.z * 64, t = threadIdx.x;
  const int Y = hy * 8 + py;
  #pragma unroll
  for (int j = 0; j < 32; ++j) {
    int flat = j * 256 + t;            // 64 c x 128 X
    int ci = flat >> 7, X = flat & 127;
    xs[ci][X] = x[(size_t)(c0 + ci) * 16384 + (size_t)Y * 128 + X];
  }
  __syncthreads();
  #pragma unroll
  for (int i = 0; i < 32; ++i) {
    int flat = i * 256 + t;            // 128 (px,hx) rows x 64 c
    int r = flat >> 6, c = flat & 63;
    int px = r >> 4, hx = r & 15;
    int row = (py * 8 + px) * 256 + hy * 16 + hx;
    q[(size_t)row * 512 + c0 + c] = (bf16)xs[c][hx * 8 + px];
  }
}

// ---------------------------------------------------------------------------
// ctx prep per window: pooled 8x8 gather, LN over C, token mixing, residual.
// Writes ctx_bf16[(m*256+s)*512 + c].
__global__ __launch_bounds__(512) void k_ctx(const float* __restrict__ xp2t,
                                             const float* __restrict__ mix_w,
                                             const float* __restrict__ mix_b,
                                             const float* __restrict__ lnw,
                                             const float* __restrict__ lnb,
                                             bf16* __restrict__ ctx) {
  __shared__ bf16 pwln[64][512];       // 64 KB
  __shared__ bf16 mwl[8][64][64];      // 64 KB
  __shared__ float smu[64], srs[64];
  const int s = blockIdx.x, wy = s >> 4, wx = s & 15;
  const int t = threadIdx.x, wv = t >> 6, lane = t & 63;

  // stage mix_w -> bf16 LDS
  #pragma unroll 4
  for (int i = 0; i < 64; ++i) {
    int idx = i * 512 + t;
    ((bf16*)mwl)[idx] = (bf16)mix_w[idx];
  }

  // load pooled window + LN stats (wave wv owns pixels wv*8 .. wv*8+7)
  for (int i = 0; i < 8; ++i) {
    const int l = wv * 8 + i;
    const int py = l >> 3, px = l & 7;
    const int y2 = wy * 4 - 2 + py, x2 = wx * 4 - 2 + px;
    const bool inb = (y2 >= 0) && (y2 < 64) && (x2 >= 0) && (x2 < 64);
    float sum = 0.f, ssq = 0.f;
    const float* src = xp2t + (size_t)(y2 * 64 + x2) * 512;
    #pragma unroll
    for (int k = 0; k < 8; ++k) {
      float v = 0.f;
      if (inb) v = src[k * 64 + lane];
      sum += v; ssq += v * v;
      pwln[l][k * 64 + lane] = (bf16)v;
    }
    #pragma unroll
    for (int off = 32; off > 0; off >>= 1) {
      sum += __shfl_down(sum, off);
      ssq += __shfl_down(ssq, off);
    }
    if (lane == 0) {
      float mu = sum * (1.f / 512.f);
      float var = ssq * (1.f / 512.f) - mu * mu;
      smu[l] = mu;
      srs[l] = rsqrtf(var + 1e-6f);
    }
  }
  __syncthreads();

  // LayerNorm in place; thread t owns channel c=t
  {
    const int c = t;
    const float w = lnw[c], b = lnb[c];
    #pragma unroll 8
    for (int l = 0; l < 64; ++l) {
      float v = (float)pwln[l][c];
      pwln[l][c] = (bf16)((v - smu[l]) * srs[l] * w + b);
    }
  }
  __syncthreads();

  // token mixing + residual; head h = c>>6 is wave-uniform
  {
    const int c = t, h = c >> 6;
    float v[64];
    #pragma unroll 8
    for (int l = 0; l < 64; ++l) v[l] = (float)pwln[l][c];
    for (int m = 0; m < 64; ++m) {
      const bf16x2* mwrow = (const bf16x2*)(&mwl[h][m][0]);
      float a0 = 0.f, a1 = 0.f;
      #pragma unroll
      for (int l2 = 0; l2 < 32; ++l2) {
        bf16x2 u = mwrow[l2];
        a0 += v[2 * l2]     * (float)u.x;
        a1 += v[2 * l2 + 1] * (float)u.y;
      }
      float res = (float)pwln[m][c] + a0 + a1 + mix_b[h * 64 + m];
      ctx[((size_t)m * 256 + s) * 512 + c] = (bf16)res;
    }
  }
}

// ---------------------------------------------------------------------------
// GEMM C[M,N] = A[M,K=512] @ B[N,K=512]^T + bias, bf16 in, fp32 accum.
// 128x128 tile, BK=32, 4 waves, global_load_lds(16B) staging.
// MODE 0: Q proj  -> O0 bf16 [l,h,s,d]
// MODE 1: KV proj -> cols<512: K like Q into O0 ; cols>=512: V^T packed into O1 [l,h,d,s]
// MODE 2: out proj-> O0 bf16 [row*512+col]
template <int MODE>
__global__ __launch_bounds__(256, 2) void k_gemm(const bf16* __restrict__ A,
                                                 const bf16* __restrict__ B,
                                                 const float* __restrict__ bias,
                                                 bf16* __restrict__ O0,
                                                 bf16* __restrict__ O1) {
  __shared__ bf16 As[4096];
  __shared__ bf16 Bs[4096];
  const int t = threadIdx.x, wv = t >> 6, ln = t & 63;
  const int bm = blockIdx.y, bn = blockIdx.x;
  const int wm = wv >> 1, wn = wv & 1;
  f32x4 acc[4][4] = {};

  const int srow = wv * 32 + (ln >> 2);
  const int scolb = (ln & 3) * 16;
  const char* ga = (const char*)A + ((size_t)(bm * 128 + srow) * 512) * 2 + scolb;
  const char* gb = (const char*)B + ((size_t)(bn * 128 + srow) * 512) * 2 + scolb;
  bf16* lA = As + wv * 1024;  // wv*2048 bytes
  bf16* lB = Bs + wv * 1024;

  for (int k0 = 0; k0 < 512; k0 += 32) {
    gll16(ga + k0 * 2,            lA);
    gll16(ga + k0 * 2 + 16 * 1024, lA + 512);
    gll16(gb + k0 * 2,            lB);
    gll16(gb + k0 * 2 + 16 * 1024, lB + 512);
    __syncthreads();
    bf16x8 af[4], bfr[4];
    #pragma unroll
    for (int m = 0; m < 4; ++m)
      af[m] = *(const bf16x8*)(As + (wm * 64 + m * 16 + (ln & 15)) * 32 + (ln >> 4) * 8);
    #pragma unroll
    for (int n = 0; n < 4; ++n)
      bfr[n] = *(const bf16x8*)(Bs + (wn * 64 + n * 16 + (ln & 15)) * 32 + (ln >> 4) * 8);
    #pragma unroll
    for (int m = 0; m < 4; ++m) {
      #pragma unroll
      for (int n = 0; n < 4; ++n) acc[m][n] = MFMA(af[m], bfr[n], acc[m][n]);
    }
    __syncthreads();
  }

  const int r0 = bm * 128 + wm * 64 + (ln >> 4) * 4;
  const int c0 = bn * 128 + wn * 64 + (ln & 15);
  #pragma unroll
  for (int m = 0; m < 4; ++m) {
    const int rg0 = r0 + m * 16;
    #pragma unroll
    for (int n = 0; n < 4; ++n) {
      const int cg = c0 + n * 16;
      const float bv = bias[cg];
      if constexpr (MODE == 2) {
        #pragma unroll
        for (int j = 0; j < 4; ++j)
          O0[(size_t)(rg0 + j) * 512 + cg] = (bf16)(acc[m][n][j] + bv);
      } else if constexpr (MODE == 0) {
        const int li = rg0 >> 8;
        #pragma unroll
        for (int j = 0; j < 4; ++j) {
          int sp = (rg0 + j) & 255;
          O0[(((size_t)li * 8 + (cg >> 6)) * 256 + sp) * 64 + (cg & 63)] =
              (bf16)(acc[m][n][j] + bv);
        }
      } else {  // MODE 1
        const int li = rg0 >> 8;
        if (cg < 512) {
          #pragma unroll
          for (int j = 0; j < 4; ++j) {
            int sp = (rg0 + j) & 255;
            O0[(((size_t)li * 8 + (cg >> 6)) * 256 + sp) * 64 + (cg & 63)] =
                (bf16)(acc[m][n][j] + bv);
          }
        } else {
          const int e = cg - 512, hh = e >> 6, d = e & 63;
          const int sp = rg0 & 255;
          bf16x4 pk;
          #pragma unroll
          for (int j = 0; j < 4; ++j) pk[j] = (bf16)(acc[m][n][j] + bv);
          *(bf16x4*)(&O1[(((size_t)li * 8 + hh) * 64 + d) * 256 + sp]) = pk;
        }
      }
    }
  }
}

// ---------------------------------------------------------------------------
// Attention per (l, h, s-tile of 64): S = Q K^T (K=64), softmax over t=256, O = P V.
// Q[l,h,s,d], K[l,h,s,d], Vt[l,h,d,s] bf16. Output Oa[(l*256+s)*512 + h*64+d] bf16.
__global__ __launch_bounds__(256, 2) void k_attn(const bf16* __restrict__ Qa,
                                                 const bf16* __restrict__ Ka,
                                                 const bf16* __restrict__ Vt,
                                                 bf16* __restrict__ Oa) {
  __shared__ bf16 Ks[256][72];   // 36864 B, aliased by Vs[64][264] (33792 B)
  __shared__ bf16 Ps[64][264];   // 33792 B
  __shared__ float redm[4][64];
  __shared__ float reds[4][64];
  bf16(*Vs)[264] = (bf16(*)[264])(&Ks[0][0]);

  const int t = threadIdx.x, wv = t >> 6, ln = t & 63;
  const int st = blockIdx.x, h = blockIdx.y, li = blockIdx.z;
  const int s0 = st * 64;
  const size_t base = ((size_t)li * 8 + h) * (256 * 64);
  const bf16* Qlh = Qa + base;
  const bf16* Klh = Ka + base;
  const bf16* Vlh = Vt + base;

  // Q fragments in registers
  bf16x8 aq[4][2];
  #pragma unroll
  for (int m = 0; m < 4; ++m) {
    #pragma unroll
    for (int ks = 0; ks < 2; ++ks)
      aq[m][ks] = *(const bf16x8*)(Qlh + (size_t)(s0 + m * 16 + (ln & 15)) * 64 +
                                   ks * 32 + (ln >> 4) * 8);
  }

  // stage K
  #pragma unroll
  for (int i = 0; i < 8; ++i) {
    int u = i * 256 + t, r = u >> 3, uo = u & 7;
    *(bf16x8*)(&Ks[r][uo * 8]) = *(const bf16x8*)(Klh + (size_t)r * 64 + uo * 8);
  }
  __syncthreads();

  // S = Q K^T (raw, scale applied inside exp)
  f32x4 acc[4][4] = {};
  #pragma unroll
  for (int ks = 0; ks < 2; ++ks) {
    bf16x8 bk[4];
    #pragma unroll
    for (int n = 0; n < 4; ++n)
      bk[n] = *(const bf16x8*)(&Ks[wv * 64 + n * 16 + (ln & 15)][ks * 32 + (ln >> 4) * 8]);
    #pragma unroll
    for (int m = 0; m < 4; ++m) {
      #pragma unroll
      for (int n = 0; n < 4; ++n) acc[m][n] = MFMA(aq[m][ks], bk[n], acc[m][n]);
    }
  }

  // per-row max (within wave: over n and the 16 lanes of a row)
  #pragma unroll
  for (int m = 0; m < 4; ++m) {
    #pragma unroll
    for (int j = 0; j < 4; ++j) {
      float mx = fmaxf(fmaxf(acc[m][0][j], acc[m][1][j]), fmaxf(acc[m][2][j], acc[m][3][j]));
      #pragma unroll
      for (int off = 1; off < 16; off <<= 1) mx = fmaxf(mx, __shfl_xor(mx, off));
      if ((ln & 15) == 0) redm[wv][m * 16 + (ln >> 4) * 4 + j] = mx;
    }
  }
  __syncthreads();

  // stage V (Ks dead now; issue early to hide latency under softmax math)
  #pragma unroll
  for (int i = 0; i < 8; ++i) {
    int u = i * 256 + t, d = u >> 5, uo = u & 31;
    *(bf16x8*)(&Vs[d][uo * 8]) = *(const bf16x8*)(Vlh + (size_t)d * 256 + uo * 8);
  }

  // softmax: exp2((S - gmax)*scale*log2e), row sums, P -> bf16 LDS
  const float SC = 0.125f * 1.4426950408889634f;
  #pragma unroll
  for (int m = 0; m < 4; ++m) {
    #pragma unroll
    for (int j = 0; j < 4; ++j) {
      const int row = m * 16 + (ln >> 4) * 4 + j;
      float gm = fmaxf(fmaxf(redm[0][row], redm[1][row]), fmaxf(redm[2][row], redm[3][row]));
      float sm = 0.f;
      #pragma unroll
      for (int n = 0; n < 4; ++n) {
        float p = exp2f((acc[m][n][j] - gm) * SC);
        acc[m][n][j] = p;
        sm += p;
      }
      #pragma unroll
      for (int off = 1; off < 16; off <<= 1) sm += __shfl_xor(sm, off);
      if ((ln & 15) == 0) reds[wv][row] = sm;
      #pragma unroll
      for (int n = 0; n < 4; ++n)
        Ps[row][wv * 64 + n * 16 + (ln & 15)] = (bf16)acc[m][n][j];
    }
  }
  __syncthreads();

  // O = P V ; wave wv owns output cols wv*16..wv*16+15
  f32x4 ao[4] = {};
  #pragma unroll
  for (int ks = 0; ks < 8; ++ks) {
    bf16x8 bv = *(const bf16x8*)(&Vs[wv * 16 + (ln & 15)][ks * 32 + (ln >> 4) * 8]);
    #pragma unroll
    for (int m = 0; m < 4; ++m) {
      bf16x8 ap = *(const bf16x8*)(&Ps[m * 16 + (ln & 15)][ks * 32 + (ln >> 4) * 8]);
      ao[m] = MFMA(ap, bv, ao[m]);
    }
  }

  // epilogue: divide by row sum, store
  #pragma unroll
  for (int m = 0; m < 4; ++m) {
    #pragma unroll
    for (int j = 0; j < 4; ++j) {
      const int row = m * 16 + (ln >> 4) * 4 + j;
      float gs = (reds[0][row] + reds[1][row]) + (reds[2][row] + reds[3][row]);
      float v = ao[m][j] * (1.f / gs);
      Oa[((size_t)li * 256 + s0 + row) * 512 + h * 64 + wv * 16 + (ln & 15)] = (bf16)v;
    }
  }
}

// ---------------------------------------------------------------------------
// o_tmp[(l*256+s)*512 + e] bf16 -> out[e][Y][X] fp32 (coalesced via LDS transpose)
__global__ void k_orelay(const bf16* __restrict__ o_tmp, float* __restrict__ out) {
  __shared__ bf16 buf[64][130];
  const int hy = blockIdx.x, py = blockIdx.y, e0 = blockIdx.z * 64, t = threadIdx.x;
  #pragma unroll
  for (int i = 0; i < 32; ++i) {
    int flat = i * 256 + t;            // 128 (px,hx) x 64 e
    int r = flat >> 6, e = flat & 63;
    int px = r >> 4, hx = r & 15;
    buf[e][hx * 8 + px] =
        o_tmp[((size_t)(py * 8 + px) * 256 + hy * 16 + hx) * 512 + e0 + e];
  }
  __syncthreads();
  const int Y = hy * 8 + py;
  #pragma unroll
  for (int i = 0; i < 32; ++i) {
    int flat = i * 256 + t;            // 64 e x 128 X
    int e = flat >> 7, X = flat & 127;
    out[(size_t)(e0 + e) * 16384 + (size_t)Y * 128 + X] = (float)buf[e][X];
  }
}

// ---------------------------------------------------------------------------
extern "C" void kernel_launch(void* const* d_in, const int* in_sizes, int n_in,
                              void* d_out, int out_size, void* d_ws, size_t ws_size,
                              hipStream_t stream) {
  const float* x     = (const float*)d_in[0];
  const float* ln_w  = (const float*)d_in[1];
  const float* ln_b  = (const float*)d_in[2];
  const float* mix_w = (const float*)d_in[3];
  const float* mix_b = (const float*)d_in[4];
  const float* in_w  = (const float*)d_in[5];
  const float* in_b  = (const float*)d_in[6];
  const float* out_w = (const float*)d_in[7];
  const float* out_b = (const float*)d_in[8];
  float* out = (float*)d_out;
  char* ws = (char*)d_ws;

  const size_t MB = 1u << 20;
  // Live ranges (aliased): xp2t dead after k_ctx; qb dead after gemm<0>;
  // ctxb dead after gemm<1>. Total requirement: 90 MB.
  float* xp2t = (float*)(ws);                      // [0, 8MB)
  bf16* qb    = (bf16*)(ws + 8 * MB);              // [8, 24MB)
  bf16* ctxb  = (bf16*)(ws + 24 * MB);             // [24, 40MB)
  bf16* wib   = (bf16*)(ws + 40 * MB);             // 1.5 MB
  bf16* wob   = (bf16*)(ws + 40 * MB + 1572864);   // 0.5 MB
  bf16* Qa    = (bf16*)(ws + 42 * MB);             // [42, 58MB)
  bf16* Ka    = (bf16*)(ws + 58 * MB);             // [58, 74MB)
  bf16* Vt    = (bf16*)(ws + 74 * MB);             // [74, 90MB)
  bf16* oatt  = (bf16*)(ws);                       // alias [0, 16MB)
  bf16* otmp  = (bf16*)(ws + 16 * MB);             // alias [16, 32MB)

  k_wconv<<<1024, 256, 0, stream>>>(in_w, out_w, wib, wob);
  k_pool<<<dim3(64, 4), 256, 0, stream>>>(x, xp2t);
  k_qprep<<<dim3(16, 8, 8), 256, 0, stream>>>(x, qb);
  k_ctx<<<256, 512, 0, stream>>>(xp2t, mix_w, mix_b, ln_w, ln_b, ctxb);
  k_gemm<0><<<dim3(4, 128), 256, 0, stream>>>(qb, wib, in_b, Qa, nullptr);
  k_gemm<1><<<dim3(8, 128), 256, 0, stream>>>(ctxb, wib + 512 * 512, in_b + 512, Ka, Vt);
  k_attn<<<dim3(4, 8, 64), 256, 0, stream>>>(Qa, Ka, Vt, oatt);
  k_gemm<2><<<dim3(4, 128), 256, 0, stream>>>(oatt, wob, out_b, otmp, nullptr);
  k_orelay<<<dim3(16, 8, 8), 256, 0, stream>>>(otmp, out);
}

// Round 2
// 171.228 us; speedup vs baseline: 1.3399x; 1.3399x over previous
//
#include <hip/hip_runtime.h>

// ---------------------------------------------------------------------------
// LargeWindowAttention on MI355X (gfx950)
// Pipeline: pool -> ln -> mix(MFMA) / q relayout -> QKV GEMMs (bf16 MFMA) ->
//           batched window attention -> out GEMM -> image relayout.
// All matmuls: mfma_f32_16x16x32_bf16, fp32 accum. Softmax/LN stats fp32.
// ---------------------------------------------------------------------------

typedef __bf16 bf16;
typedef __bf16 bf16x2 __attribute__((ext_vector_type(2)));
typedef __bf16 bf16x4 __attribute__((ext_vector_type(4)));
typedef __bf16 bf16x8 __attribute__((ext_vector_type(8)));
typedef float f32x4 __attribute__((ext_vector_type(4)));

#define MFMA(a, b, c) __builtin_amdgcn_mfma_f32_16x16x32_bf16(a, b, c, 0, 0, 0)

__device__ __forceinline__ void gll16(const void* g, void* l) {
  __builtin_amdgcn_global_load_lds((const __attribute__((address_space(1))) void*)g,
                                   (__attribute__((address_space(3))) void*)l, 16, 0, 0);
}

// ---------------------------------------------------------------------------
// Convert in_w (1536x512) and out_w (512x512) fp32 -> bf16
__global__ void k_wconv(const float* __restrict__ in_w, const float* __restrict__ out_w,
                        bf16* __restrict__ wib, bf16* __restrict__ wob) {
  int i = blockIdx.x * blockDim.x + threadIdx.x;
  const int n1 = (1536 * 512) / 4;
  float4 v;
  bf16* dst;
  if (i < n1) { v = ((const float4*)in_w)[i];      dst = wib + (size_t)i * 4; }
  else        { v = ((const float4*)out_w)[i - n1]; dst = wob + (size_t)(i - n1) * 4; }
  dst[0] = (bf16)v.x; dst[1] = (bf16)v.y; dst[2] = (bf16)v.z; dst[3] = (bf16)v.w;
}

// ---------------------------------------------------------------------------
// 2x2 average pool of x[512][128][128] -> xp2t[y2][x2][c]  (c-contiguous)
__global__ void k_pool(const float* __restrict__ x, float* __restrict__ xp2t) {
  __shared__ float pooled[128][65];
  const int y2 = blockIdx.x, c0 = blockIdx.y * 128, t = threadIdx.x;
  #pragma unroll
  for (int i = 0; i < 32; ++i) {
    int flat = i * 256 + t;
    int ci = flat >> 6, x2 = flat & 63;
    const float* p = x + (size_t)(c0 + ci) * 16384 + (size_t)(2 * y2) * 128 + 2 * x2;
    float2 a = *(const float2*)p;
    float2 b = *(const float2*)(p + 128);
    pooled[ci][x2] = 0.25f * (a.x + a.y + b.x + b.y);
  }
  __syncthreads();
  #pragma unroll
  for (int j = 0; j < 32; ++j) {
    int flat = j * 256 + t;
    int x2 = flat >> 7, ci = flat & 127;
    xp2t[(size_t)(y2 * 64 + x2) * 512 + c0 + ci] = pooled[ci][x2];
  }
}

// ---------------------------------------------------------------------------
// q relayout: x[c][Y][X] -> q_bf16[(l*256+s)*512 + c], l=py*8+px, s=hy*16+hx
__global__ void k_qprep(const float* __restrict__ x, bf16* __restrict__ q) {
  __shared__ float xs[64][129];
  const int hy = blockIdx.x, py = blockIdx.y, c0 = blockIdx.z * 64, t = threadIdx.x;
  const int Y = hy * 8 + py;
  #pragma unroll
  for (int j = 0; j < 32; ++j) {
    int flat = j * 256 + t;
    int ci = flat >> 7, X = flat & 127;
    xs[ci][X] = x[(size_t)(c0 + ci) * 16384 + (size_t)Y * 128 + X];
  }
  __syncthreads();
  #pragma unroll
  for (int i = 0; i < 32; ++i) {
    int flat = i * 256 + t;
    int r = flat >> 6, c = flat & 63;
    int px = r >> 4, hx = r & 15;
    int row = (py * 8 + px) * 256 + hy * 16 + hx;
    q[(size_t)row * 512 + c0 + c] = (bf16)xs[c][hx * 8 + px];
  }
}

// ---------------------------------------------------------------------------
// LN per window: gather pooled 8x8 (OOB->0), fp32 stats via 64-lane butterfly,
// normalize in registers, LDS-transpose, write T[s][c][l] bf16.
__global__ __launch_bounds__(512) void k_ln(const float* __restrict__ xp2t,
                                            const float* __restrict__ lnw,
                                            const float* __restrict__ lnb,
                                            bf16* __restrict__ T) {
  __shared__ bf16 Tt[512][72];  // 72 KB; pitch 144B -> 8-way (b128-optimal)
  const int s = blockIdx.x, wy = s >> 4, wx = s & 15;
  const int t = threadIdx.x, wv = t >> 6, ln = t & 63;

  float wl[8], bl[8];
  #pragma unroll
  for (int k = 0; k < 8; ++k) { wl[k] = lnw[k * 64 + ln]; bl[k] = lnb[k * 64 + ln]; }

  #pragma unroll
  for (int i = 0; i < 8; i += 2) {
    float v[2][8], mu_[2], rs_[2];
    #pragma unroll
    for (int p = 0; p < 2; ++p) {
      const int l = wv * 8 + i + p;
      const int py = l >> 3, px = l & 7;
      const int y2 = wy * 4 - 2 + py, x2 = wx * 4 - 2 + px;
      const bool inb = (y2 >= 0) && (y2 < 64) && (x2 >= 0) && (x2 < 64);
      const float* src = xp2t + (size_t)(y2 * 64 + x2) * 512;
      float sum = 0.f, ssq = 0.f;
      #pragma unroll
      for (int k = 0; k < 8; ++k) {
        float xv = 0.f;
        if (inb) xv = src[k * 64 + ln];
        v[p][k] = xv; sum += xv; ssq += xv * xv;
      }
      #pragma unroll
      for (int off = 1; off < 64; off <<= 1) {
        sum += __shfl_xor(sum, off);
        ssq += __shfl_xor(ssq, off);
      }
      float mu = sum * (1.f / 512.f);
      mu_[p] = mu;
      rs_[p] = rsqrtf(ssq * (1.f / 512.f) - mu * mu + 1e-6f);
    }
    const int l0 = wv * 8 + i;  // even
    #pragma unroll
    for (int k = 0; k < 8; ++k) {
      const int c = k * 64 + ln;
      bf16x2 u;
      u.x = (bf16)((v[0][k] - mu_[0]) * rs_[0] * wl[k] + bl[k]);
      u.y = (bf16)((v[1][k] - mu_[1]) * rs_[1] * wl[k] + bl[k]);
      *(bf16x2*)(&Tt[c][l0]) = u;
    }
  }
  __syncthreads();
  // write out T[s][c][l]: bf16x8 chunks, fully coalesced
  #pragma unroll
  for (int it = 0; it < 8; ++it) {
    int flat = it * 512 + t;           // (c in 512) x (chunk in 8)
    int c = flat >> 3, ch = flat & 7;
    bf16x8 u = *(const bf16x8*)(&Tt[c][ch * 8]);
    *(bf16x8*)(T + ((size_t)s * 512 + c) * 64 + ch * 8) = u;
  }
}

// ---------------------------------------------------------------------------
// Token mixing via MFMA: D[m][c'] = sum_l (mix_w[h][m][l] + I) * T[c'][l],
// + mix_b[h][m]. Output ctx[(m*256+s)*512 + h*64+c'] bf16. No LDS.
__global__ __launch_bounds__(256) void k_mix(const bf16* __restrict__ T,
                                             const float* __restrict__ mix_w,
                                             const float* __restrict__ mix_b,
                                             bf16* __restrict__ ctx) {
  const int t = threadIdx.x, wv = t >> 6, ln = t & 63;
  const int s = blockIdx.x, hg = blockIdx.y;
  const int h = hg * 4 + wv;
  const int q = ln >> 4, r = ln & 15;

  bf16x8 a[4][2];
  #pragma unroll
  for (int m = 0; m < 4; ++m) {
    #pragma unroll
    for (int ks = 0; ks < 2; ++ks) {
      const int rm = m * 16 + r;
      const float* wsrc = mix_w + ((size_t)h * 64 + rm) * 64 + ks * 32 + q * 8;
      bf16x8 pk;
      #pragma unroll
      for (int e = 0; e < 8; ++e) {
        int l = ks * 32 + q * 8 + e;
        float w = wsrc[e] + (rm == l ? 1.f : 0.f);
        pk[e] = (bf16)w;
      }
      a[m][ks] = pk;
    }
  }
  const bf16* Tb = T + ((size_t)s * 512 + h * 64) * 64;
  bf16x8 b[4][2];
  #pragma unroll
  for (int n = 0; n < 4; ++n) {
    #pragma unroll
    for (int ks = 0; ks < 2; ++ks)
      b[n][ks] = *(const bf16x8*)(Tb + (size_t)(n * 16 + r) * 64 + ks * 32 + q * 8);
  }
  f32x4 acc[4][4] = {};
  #pragma unroll
  for (int ks = 0; ks < 2; ++ks) {
    #pragma unroll
    for (int m = 0; m < 4; ++m) {
      #pragma unroll
      for (int n = 0; n < 4; ++n) acc[m][n] = MFMA(a[m][ks], b[n][ks], acc[m][n]);
    }
  }
  #pragma unroll
  for (int m = 0; m < 4; ++m) {
    #pragma unroll
    for (int j = 0; j < 4; ++j) {
      const int rm = m * 16 + q * 4 + j;
      const float bias = mix_b[h * 64 + rm];
      #pragma unroll
      for (int n = 0; n < 4; ++n)
        ctx[((size_t)rm * 256 + s) * 512 + h * 64 + n * 16 + r] =
            (bf16)(acc[m][n][j] + bias);
    }
  }
}

// ---------------------------------------------------------------------------
// GEMM C[M,N] = A[M,K=512] @ B[N,K=512]^T + bias, bf16 in, fp32 accum.
// 128x128 tile, BK=32, 4 waves, global_load_lds(16B) staging.
template <int MODE>
__global__ __launch_bounds__(256, 2) void k_gemm(const bf16* __restrict__ A,
                                                 const bf16* __restrict__ B,
                                                 const float* __restrict__ bias,
                                                 bf16* __restrict__ O0,
                                                 bf16* __restrict__ O1) {
  __shared__ bf16 As[4096];
  __shared__ bf16 Bs[4096];
  const int t = threadIdx.x, wv = t >> 6, ln = t & 63;
  const int bm = blockIdx.y, bn = blockIdx.x;
  const int wm = wv >> 1, wn = wv & 1;
  f32x4 acc[4][4] = {};

  const int srow = wv * 32 + (ln >> 2);
  const int scolb = (ln & 3) * 16;
  const char* ga = (const char*)A + ((size_t)(bm * 128 + srow) * 512) * 2 + scolb;
  const char* gb = (const char*)B + ((size_t)(bn * 128 + srow) * 512) * 2 + scolb;
  bf16* lA = As + wv * 1024;
  bf16* lB = Bs + wv * 1024;

  for (int k0 = 0; k0 < 512; k0 += 32) {
    gll16(ga + k0 * 2,             lA);
    gll16(ga + k0 * 2 + 16 * 1024, lA + 512);
    gll16(gb + k0 * 2,             lB);
    gll16(gb + k0 * 2 + 16 * 1024, lB + 512);
    __syncthreads();
    bf16x8 af[4], bfr[4];
    #pragma unroll
    for (int m = 0; m < 4; ++m)
      af[m] = *(const bf16x8*)(As + (wm * 64 + m * 16 + (ln & 15)) * 32 + (ln >> 4) * 8);
    #pragma unroll
    for (int n = 0; n < 4; ++n)
      bfr[n] = *(const bf16x8*)(Bs + (wn * 64 + n * 16 + (ln & 15)) * 32 + (ln >> 4) * 8);
    #pragma unroll
    for (int m = 0; m < 4; ++m) {
      #pragma unroll
      for (int n = 0; n < 4; ++n) acc[m][n] = MFMA(af[m], bfr[n], acc[m][n]);
    }
    __syncthreads();
  }

  const int r0 = bm * 128 + wm * 64 + (ln >> 4) * 4;
  const int c0 = bn * 128 + wn * 64 + (ln & 15);
  #pragma unroll
  for (int m = 0; m < 4; ++m) {
    const int rg0 = r0 + m * 16;
    #pragma unroll
    for (int n = 0; n < 4; ++n) {
      const int cg = c0 + n * 16;
      const float bv = bias[cg];
      if constexpr (MODE == 2) {
        #pragma unroll
        for (int j = 0; j < 4; ++j)
          O0[(size_t)(rg0 + j) * 512 + cg] = (bf16)(acc[m][n][j] + bv);
      } else if constexpr (MODE == 0) {
        const int li = rg0 >> 8;
        #pragma unroll
        for (int j = 0; j < 4; ++j) {
          int sp = (rg0 + j) & 255;
          O0[(((size_t)li * 8 + (cg >> 6)) * 256 + sp) * 64 + (cg & 63)] =
              (bf16)(acc[m][n][j] + bv);
        }
      } else {  // MODE 1
        const int li = rg0 >> 8;
        if (cg < 512) {
          #pragma unroll
          for (int j = 0; j < 4; ++j) {
            int sp = (rg0 + j) & 255;
            O0[(((size_t)li * 8 + (cg >> 6)) * 256 + sp) * 64 + (cg & 63)] =
                (bf16)(acc[m][n][j] + bv);
          }
        } else {
          const int e = cg - 512, hh = e >> 6, d = e & 63;
          const int sp = rg0 & 255;
          bf16x4 pk;
          #pragma unroll
          for (int j = 0; j < 4; ++j) pk[j] = (bf16)(acc[m][n][j] + bv);
          *(bf16x4*)(&O1[(((size_t)li * 8 + hh) * 64 + d) * 256 + sp]) = pk;
        }
      }
    }
  }
}

// ---------------------------------------------------------------------------
// Attention per (l, h, s-tile of 64): S = Q K^T, softmax over t=256, O = P V.
// Q[l,h,s,d], K[l,h,s,d], Vt[l,h,d,s] bf16 -> Oa[(l*256+s)*512 + h*64+d] bf16.
// LDS: Ks[256][72] aliased by Ps[64][264] (union). V read global->reg.
// Block-id swizzle groups the 4 st-siblings of each (l,h) on one XCD.
__global__ __launch_bounds__(256, 4) void k_attn(const bf16* __restrict__ Qa,
                                                 const bf16* __restrict__ Ka,
                                                 const bf16* __restrict__ Vt,
                                                 bf16* __restrict__ Oa) {
  __shared__ __align__(16) char KP[36864];  // union: Ks 256x72 / Ps 64x264
  __shared__ float redm[4][64];
  __shared__ float reds[4][64];
  bf16(*Ks)[72]  = (bf16(*)[72])KP;
  bf16(*Ps)[264] = (bf16(*)[264])KP;

  const int t = threadIdx.x, wv = t >> 6, ln = t & 63;
  const int q = ln >> 4, r = ln & 15;
  const int bid = blockIdx.x;
  const int st = (bid >> 3) & 3;                    // siblings share bid%8 -> XCD
  const int lh = (bid & 7) | ((bid >> 5) << 3);
  const int s0 = st * 64;
  const size_t base = (size_t)lh * (256 * 64);
  const bf16* Qlh = Qa + base;
  const bf16* Klh = Ka + base;
  const bf16* Vlh = Vt + base;

  // Q fragments in registers
  bf16x8 aq[4][2];
  #pragma unroll
  for (int m = 0; m < 4; ++m) {
    #pragma unroll
    for (int ks = 0; ks < 2; ++ks)
      aq[m][ks] = *(const bf16x8*)(Qlh + (size_t)(s0 + m * 16 + r) * 64 + ks * 32 + q * 8);
  }

  // stage K -> LDS
  #pragma unroll
  for (int i = 0; i < 8; ++i) {
    int u = i * 256 + t, rr = u >> 3, uo = u & 7;
    *(bf16x8*)(&Ks[rr][uo * 8]) = *(const bf16x8*)(Klh + (size_t)rr * 64 + uo * 8);
  }
  __syncthreads();

  // S = Q K^T
  f32x4 acc[4][4] = {};
  #pragma unroll
  for (int ks = 0; ks < 2; ++ks) {
    bf16x8 bk[4];
    #pragma unroll
    for (int n = 0; n < 4; ++n)
      bk[n] = *(const bf16x8*)(&Ks[wv * 64 + n * 16 + r][ks * 32 + q * 8]);
    #pragma unroll
    for (int m = 0; m < 4; ++m) {
      #pragma unroll
      for (int n = 0; n < 4; ++n) acc[m][n] = MFMA(aq[m][ks], bk[n], acc[m][n]);
    }
  }

  // per-row max within wave's 64 t-cols
  #pragma unroll
  for (int m = 0; m < 4; ++m) {
    #pragma unroll
    for (int j = 0; j < 4; ++j) {
      float mx = fmaxf(fmaxf(acc[m][0][j], acc[m][1][j]), fmaxf(acc[m][2][j], acc[m][3][j]));
      #pragma unroll
      for (int off = 1; off < 16; off <<= 1) mx = fmaxf(mx, __shfl_xor(mx, off));
      if (r == 0) redm[wv][m * 16 + q * 4 + j] = mx;
    }
  }
  __syncthreads();  // also: all waves done reading Ks -> Ps alias safe

  // V fragments global->reg (in flight during softmax)
  bf16x8 bv[8];
  #pragma unroll
  for (int ks = 0; ks < 8; ++ks)
    bv[ks] = *(const bf16x8*)(Vlh + (size_t)(wv * 16 + r) * 256 + ks * 32 + q * 8);

  // softmax: P = exp2((S - gmax)*scale*log2e), row sums, P -> bf16 LDS
  const float SC = 0.125f * 1.4426950408889634f;
  #pragma unroll
  for (int m = 0; m < 4; ++m) {
    #pragma unroll
    for (int j = 0; j < 4; ++j) {
      const int row = m * 16 + q * 4 + j;
      float gm = fmaxf(fmaxf(redm[0][row], redm[1][row]), fmaxf(redm[2][row], redm[3][row]));
      float sm = 0.f;
      #pragma unroll
      for (int n = 0; n < 4; ++n) {
        float p = exp2f((acc[m][n][j] - gm) * SC);
        acc[m][n][j] = p;
        sm += p;
      }
      #pragma unroll
      for (int off = 1; off < 16; off <<= 1) sm += __shfl_xor(sm, off);
      if (r == 0) reds[wv][row] = sm;
      #pragma unroll
      for (int n = 0; n < 4; ++n)
        Ps[row][wv * 64 + n * 16 + r] = (bf16)acc[m][n][j];
    }
  }
  __syncthreads();

  // O = P V ; wave wv owns d-cols wv*16..wv*16+15
  f32x4 ao[4] = {};
  #pragma unroll
  for (int ks = 0; ks < 8; ++ks) {
    #pragma unroll
    for (int m = 0; m < 4; ++m) {
      bf16x8 ap = *(const bf16x8*)(&Ps[m * 16 + r][ks * 32 + q * 8]);
      ao[m] = MFMA(ap, bv[ks], ao[m]);
    }
  }

  // epilogue: divide by global row sum, store
  #pragma unroll
  for (int m = 0; m < 4; ++m) {
    #pragma unroll
    for (int j = 0; j < 4; ++j) {
      const int row = m * 16 + q * 4 + j;
      float gs = (reds[0][row] + reds[1][row]) + (reds[2][row] + reds[3][row]);
      float v = ao[m][j] * (1.f / gs);
      Oa[((size_t)(lh >> 3) * 256 + s0 + row) * 512 + (lh & 7) * 64 + wv * 16 + r] = (bf16)v;
    }
  }
}

// ---------------------------------------------------------------------------
// o_tmp[(l*256+s)*512 + e] bf16 -> out[e][Y][X] fp32
__global__ void k_orelay(const bf16* __restrict__ o_tmp, float* __restrict__ out) {
  __shared__ bf16 buf[64][130];
  const int hy = blockIdx.x, py = blockIdx.y, e0 = blockIdx.z * 64, t = threadIdx.x;
  #pragma unroll
  for (int i = 0; i < 32; ++i) {
    int flat = i * 256 + t;
    int r = flat >> 6, e = flat & 63;
    int px = r >> 4, hx = r & 15;
    buf[e][hx * 8 + px] =
        o_tmp[((size_t)(py * 8 + px) * 256 + hy * 16 + hx) * 512 + e0 + e];
  }
  __syncthreads();
  const int Y = hy * 8 + py;
  #pragma unroll
  for (int i = 0; i < 32; ++i) {
    int flat = i * 256 + t;
    int e = flat >> 7, X = flat & 127;
    out[(size_t)(e0 + e) * 16384 + (size_t)Y * 128 + X] = (float)buf[e][X];
  }
}

// ---------------------------------------------------------------------------
extern "C" void kernel_launch(void* const* d_in, const int* in_sizes, int n_in,
                              void* d_out, int out_size, void* d_ws, size_t ws_size,
                              hipStream_t stream) {
  const float* x     = (const float*)d_in[0];
  const float* ln_w  = (const float*)d_in[1];
  const float* ln_b  = (const float*)d_in[2];
  const float* mix_w = (const float*)d_in[3];
  const float* mix_b = (const float*)d_in[4];
  const float* in_w  = (const float*)d_in[5];
  const float* in_b  = (const float*)d_in[6];
  const float* out_w = (const float*)d_in[7];
  const float* out_b = (const float*)d_in[8];
  float* out = (float*)d_out;
  char* ws = (char*)d_ws;

  const size_t MB = 1u << 20;
  // Lifetime-aliased map (74 MB total):
  // [0,8)   xp2t      (pool -> ln)        then Ka [0,16)   (gemm1 -> attn)
  // [8,24)  qb        (qprep -> gemm0)
  // [16,32)           Vt                  (gemm1 -> attn)
  // [24,40) Tn        (ln -> mix)
  // [32,48)           oatt                (attn -> gemm2)
  // [40,56) ctxb      (mix -> gemm1)
  // [48,64)           otmp                (gemm2 -> orelay)
  // [56,72) Qa        (gemm0 -> attn)
  // [72,74) wib/wob
  float* xp2t = (float*)(ws);
  bf16* qb    = (bf16*)(ws + 8 * MB);
  bf16* Tn    = (bf16*)(ws + 24 * MB);
  bf16* ctxb  = (bf16*)(ws + 40 * MB);
  bf16* Qa    = (bf16*)(ws + 56 * MB);
  bf16* Ka    = (bf16*)(ws);
  bf16* Vt    = (bf16*)(ws + 16 * MB);
  bf16* oatt  = (bf16*)(ws + 32 * MB);
  bf16* otmp  = (bf16*)(ws + 48 * MB);
  bf16* wib   = (bf16*)(ws + 72 * MB);
  bf16* wob   = (bf16*)(ws + 72 * MB + 1572864);

  k_wconv<<<1024, 256, 0, stream>>>(in_w, out_w, wib, wob);
  k_pool<<<dim3(64, 4), 256, 0, stream>>>(x, xp2t);
  k_qprep<<<dim3(16, 8, 8), 256, 0, stream>>>(x, qb);
  k_ln<<<256, 512, 0, stream>>>(xp2t, ln_w, ln_b, Tn);
  k_mix<<<dim3(256, 2), 256, 0, stream>>>(Tn, mix_w, mix_b, ctxb);
  k_gemm<0><<<dim3(4, 128), 256, 0, stream>>>(qb, wib, in_b, Qa, nullptr);
  k_gemm<1><<<dim3(8, 128), 256, 0, stream>>>(ctxb, wib + 512 * 512, in_b + 512, Ka, Vt);
  k_attn<<<2048, 256, 0, stream>>>(Qa, Ka, Vt, oatt);
  k_gemm<2><<<dim3(4, 128), 256, 0, stream>>>(oatt, wob, out_b, otmp, nullptr);
  k_orelay<<<dim3(16, 8, 8), 256, 0, stream>>>(otmp, out);
}

// Round 3
// 169.643 us; speedup vs baseline: 1.3524x; 1.0093x over previous
//
#include <hip/hip_runtime.h>

// ---------------------------------------------------------------------------
// LargeWindowAttention on MI355X (gfx950)
// pq(fused pool+q-relayout) -> ln -> mix(MFMA) -> QKV GEMMs (bf16 MFMA) ->
// batched window attention (wave-local softmax) -> out GEMM -> image relayout.
// ---------------------------------------------------------------------------

typedef __bf16 bf16;
typedef __bf16 bf16x2 __attribute__((ext_vector_type(2)));
typedef __bf16 bf16x4 __attribute__((ext_vector_type(4)));
typedef __bf16 bf16x8 __attribute__((ext_vector_type(8)));
typedef float f32x4 __attribute__((ext_vector_type(4)));

#define MFMA(a, b, c) __builtin_amdgcn_mfma_f32_16x16x32_bf16(a, b, c, 0, 0, 0)

__device__ __forceinline__ void gll16(const void* g, void* l) {
  __builtin_amdgcn_global_load_lds((const __attribute__((address_space(1))) void*)g,
                                   (__attribute__((address_space(3))) void*)l, 16, 0, 0);
}

// ---------------------------------------------------------------------------
// Convert in_w (1536x512) and out_w (512x512) fp32 -> bf16
__global__ void k_wconv(const float* __restrict__ in_w, const float* __restrict__ out_w,
                        bf16* __restrict__ wib, bf16* __restrict__ wob) {
  int i = blockIdx.x * blockDim.x + threadIdx.x;
  const int n1 = (1536 * 512) / 4;
  float4 v;
  bf16* dst;
  if (i < n1) { v = ((const float4*)in_w)[i];      dst = wib + (size_t)i * 4; }
  else        { v = ((const float4*)out_w)[i - n1]; dst = wob + (size_t)(i - n1) * 4; }
  dst[0] = (bf16)v.x; dst[1] = (bf16)v.y; dst[2] = (bf16)v.z; dst[3] = (bf16)v.w;
}

// ---------------------------------------------------------------------------
// Fused: read x once -> (a) 2x2 pooled xp2t[y2][x2][c] fp32, (b) q relayout
// qb[(l*256+s)*512+c] bf16.  Grid (64 y2, 8 c-chunk), 256 thr.
__global__ __launch_bounds__(256) void k_pq(const float* __restrict__ x,
                                            float* __restrict__ xp2t,
                                            bf16* __restrict__ qb) {
  __shared__ float xs[2][64][133];   // pitch 133 (odd) -> conflict-free col reads
  const int y2 = blockIdx.x, c0 = blockIdx.y * 64, t = threadIdx.x;
  #pragma unroll
  for (int it = 0; it < 16; ++it) {
    int flat = it * 256 + t;                 // ci(64) x yb(2) x xq(32)
    int ci = flat >> 6, rest = flat & 63;
    int yb = rest >> 5, xq = rest & 31;
    float4 v = *(const float4*)(x + (size_t)(c0 + ci) * 16384 +
                                (size_t)(2 * y2 + yb) * 128 + xq * 4);
    float* d = &xs[yb][ci][xq * 4];
    d[0] = v.x; d[1] = v.y; d[2] = v.z; d[3] = v.w;
  }
  __syncthreads();
  // pooled: 64 x2 x 64 ci (ci fastest -> coalesced)
  #pragma unroll
  for (int it = 0; it < 16; ++it) {
    int flat = it * 256 + t;
    int x2 = flat >> 6, ci = flat & 63;
    float s = xs[0][ci][2 * x2] + xs[0][ci][2 * x2 + 1] +
              xs[1][ci][2 * x2] + xs[1][ci][2 * x2 + 1];
    xp2t[(size_t)(y2 * 64 + x2) * 512 + c0 + ci] = 0.25f * s;
  }
  // q relayout for both rows
  #pragma unroll
  for (int yb = 0; yb < 2; ++yb) {
    const int Y = 2 * y2 + yb;
    const int hy = Y >> 3, py = Y & 7;
    #pragma unroll
    for (int it = 0; it < 32; ++it) {
      int flat = it * 256 + t;               // X(128) x ci(64)
      int X = flat >> 6, ci = flat & 63;
      int l = py * 8 + (X & 7), s = hy * 16 + (X >> 3);
      qb[((size_t)l * 256 + s) * 512 + c0 + ci] = (bf16)xs[yb][ci][X];
    }
  }
}

// ---------------------------------------------------------------------------
// LN per window-quarter: gather pooled pixels (OOB->0), fp32 stats via 64-lane
// butterfly, normalize, LDS-transpose, write T[s][c][qt*16 + 0..15] bf16.
// Grid (256 s, 4 qt), 512 thr (8 waves x 2 pixels).
__global__ __launch_bounds__(512) void k_ln(const float* __restrict__ xp2t,
                                            const float* __restrict__ lnw,
                                            const float* __restrict__ lnb,
                                            bf16* __restrict__ T) {
  __shared__ bf16 Tt[512][24];   // pitch 48B -> b128-aligned reads
  const int s = blockIdx.x, qt = blockIdx.y;
  const int wy = s >> 4, wx = s & 15;
  const int t = threadIdx.x, wv = t >> 6, ln = t & 63;

  float wl[8], bl[8];
  #pragma unroll
  for (int k = 0; k < 8; ++k) { wl[k] = lnw[k * 64 + ln]; bl[k] = lnb[k * 64 + ln]; }

  float v[2][8], mu_[2], rs_[2];
  #pragma unroll
  for (int p = 0; p < 2; ++p) {
    const int l = qt * 16 + wv * 2 + p;
    const int py = l >> 3, px = l & 7;
    const int y2 = wy * 4 - 2 + py, x2 = wx * 4 - 2 + px;
    const bool inb = (y2 >= 0) && (y2 < 64) && (x2 >= 0) && (x2 < 64);
    const float* src = xp2t + (size_t)(y2 * 64 + x2) * 512;
    float sum = 0.f, ssq = 0.f;
    #pragma unroll
    for (int k = 0; k < 8; ++k) {
      float xv = 0.f;
      if (inb) xv = src[k * 64 + ln];
      v[p][k] = xv; sum += xv; ssq += xv * xv;
    }
    #pragma unroll
    for (int off = 1; off < 64; off <<= 1) {
      sum += __shfl_xor(sum, off);
      ssq += __shfl_xor(ssq, off);
    }
    float mu = sum * (1.f / 512.f);
    mu_[p] = mu;
    rs_[p] = rsqrtf(ssq * (1.f / 512.f) - mu * mu + 1e-6f);
  }
  #pragma unroll
  for (int k = 0; k < 8; ++k) {
    const int c = k * 64 + ln;
    bf16x2 u;
    u.x = (bf16)((v[0][k] - mu_[0]) * rs_[0] * wl[k] + bl[k]);
    u.y = (bf16)((v[1][k] - mu_[1]) * rs_[1] * wl[k] + bl[k]);
    *(bf16x2*)(&Tt[c][wv * 2]) = u;
  }
  __syncthreads();
  #pragma unroll
  for (int it = 0; it < 2; ++it) {
    int flat = it * 512 + t;                 // c(512) x ch(2)
    int c = flat >> 1, ch = flat & 1;
    bf16x8 u = *(const bf16x8*)(&Tt[c][ch * 8]);
    *(bf16x8*)(T + ((size_t)s * 512 + c) * 64 + qt * 16 + ch * 8) = u;
  }
}

// ---------------------------------------------------------------------------
// Token mixing via MFMA: D[m][c'] = sum_l (mix_w[h][m][l] + I) * T[c'][l],
// + mix_b[h][m]. Output ctx[(m*256+s)*512 + h*64+c'] bf16. No LDS.
__global__ __launch_bounds__(256) void k_mix(const bf16* __restrict__ T,
                                             const float* __restrict__ mix_w,
                                             const float* __restrict__ mix_b,
                                             bf16* __restrict__ ctx) {
  const int t = threadIdx.x, wv = t >> 6, ln = t & 63;
  const int s = blockIdx.x, hg = blockIdx.y;
  const int h = hg * 4 + wv;
  const int q = ln >> 4, r = ln & 15;

  bf16x8 a[4][2];
  #pragma unroll
  for (int m = 0; m < 4; ++m) {
    #pragma unroll
    for (int ks = 0; ks < 2; ++ks) {
      const int rm = m * 16 + r;
      const float* wsrc = mix_w + ((size_t)h * 64 + rm) * 64 + ks * 32 + q * 8;
      bf16x8 pk;
      #pragma unroll
      for (int e = 0; e < 8; ++e) {
        int l = ks * 32 + q * 8 + e;
        float w = wsrc[e] + (rm == l ? 1.f : 0.f);
        pk[e] = (bf16)w;
      }
      a[m][ks] = pk;
    }
  }
  const bf16* Tb = T + ((size_t)s * 512 + h * 64) * 64;
  bf16x8 b[4][2];
  #pragma unroll
  for (int n = 0; n < 4; ++n) {
    #pragma unroll
    for (int ks = 0; ks < 2; ++ks)
      b[n][ks] = *(const bf16x8*)(Tb + (size_t)(n * 16 + r) * 64 + ks * 32 + q * 8);
  }
  f32x4 acc[4][4] = {};
  #pragma unroll
  for (int ks = 0; ks < 2; ++ks) {
    #pragma unroll
    for (int m = 0; m < 4; ++m) {
      #pragma unroll
      for (int n = 0; n < 4; ++n) acc[m][n] = MFMA(a[m][ks], b[n][ks], acc[m][n]);
    }
  }
  #pragma unroll
  for (int m = 0; m < 4; ++m) {
    #pragma unroll
    for (int j = 0; j < 4; ++j) {
      const int rm = m * 16 + q * 4 + j;
      const float bias = mix_b[h * 64 + rm];
      #pragma unroll
      for (int n = 0; n < 4; ++n)
        ctx[((size_t)rm * 256 + s) * 512 + h * 64 + n * 16 + r] =
            (bf16)(acc[m][n][j] + bias);
    }
  }
}

// ---------------------------------------------------------------------------
// GEMM C[M,N] = A[M,K=512] @ B[N,K=512]^T + bias, bf16 in, fp32 accum.
template <int MODE>
__global__ __launch_bounds__(256, 3) void k_gemm(const bf16* __restrict__ A,
                                                 const bf16* __restrict__ B,
                                                 const float* __restrict__ bias,
                                                 bf16* __restrict__ O0,
                                                 bf16* __restrict__ O1) {
  __shared__ bf16 As[4096];
  __shared__ bf16 Bs[4096];
  const int t = threadIdx.x, wv = t >> 6, ln = t & 63;
  const int bm = blockIdx.y, bn = blockIdx.x;
  const int wm = wv >> 1, wn = wv & 1;
  f32x4 acc[4][4] = {};

  const int srow = wv * 32 + (ln >> 2);
  const int scolb = (ln & 3) * 16;
  const char* ga = (const char*)A + ((size_t)(bm * 128 + srow) * 512) * 2 + scolb;
  const char* gb = (const char*)B + ((size_t)(bn * 128 + srow) * 512) * 2 + scolb;
  bf16* lA = As + wv * 1024;
  bf16* lB = Bs + wv * 1024;

  for (int k0 = 0; k0 < 512; k0 += 32) {
    gll16(ga + k0 * 2,             lA);
    gll16(ga + k0 * 2 + 16 * 1024, lA + 512);
    gll16(gb + k0 * 2,             lB);
    gll16(gb + k0 * 2 + 16 * 1024, lB + 512);
    __syncthreads();
    bf16x8 af[4], bfr[4];
    #pragma unroll
    for (int m = 0; m < 4; ++m)
      af[m] = *(const bf16x8*)(As + (wm * 64 + m * 16 + (ln & 15)) * 32 + (ln >> 4) * 8);
    #pragma unroll
    for (int n = 0; n < 4; ++n)
      bfr[n] = *(const bf16x8*)(Bs + (wn * 64 + n * 16 + (ln & 15)) * 32 + (ln >> 4) * 8);
    #pragma unroll
    for (int m = 0; m < 4; ++m) {
      #pragma unroll
      for (int n = 0; n < 4; ++n) acc[m][n] = MFMA(af[m], bfr[n], acc[m][n]);
    }
    __syncthreads();
  }

  const int r0 = bm * 128 + wm * 64 + (ln >> 4) * 4;
  const int c0 = bn * 128 + wn * 64 + (ln & 15);
  #pragma unroll
  for (int m = 0; m < 4; ++m) {
    const int rg0 = r0 + m * 16;
    #pragma unroll
    for (int n = 0; n < 4; ++n) {
      const int cg = c0 + n * 16;
      const float bv = bias[cg];
      if constexpr (MODE == 2) {
        #pragma unroll
        for (int j = 0; j < 4; ++j)
          O0[(size_t)(rg0 + j) * 512 + cg] = (bf16)(acc[m][n][j] + bv);
      } else if constexpr (MODE == 0) {
        const int li = rg0 >> 8;
        #pragma unroll
        for (int j = 0; j < 4; ++j) {
          int sp = (rg0 + j) & 255;
          O0[(((size_t)li * 8 + (cg >> 6)) * 256 + sp) * 64 + (cg & 63)] =
              (bf16)(acc[m][n][j] + bv);
        }
      } else {  // MODE 1
        const int li = rg0 >> 8;
        if (cg < 512) {
          #pragma unroll
          for (int j = 0; j < 4; ++j) {
            int sp = (rg0 + j) & 255;
            O0[(((size_t)li * 8 + (cg >> 6)) * 256 + sp) * 64 + (cg & 63)] =
                (bf16)(acc[m][n][j] + bv);
          }
        } else {
          const int e = cg - 512, hh = e >> 6, d = e & 63;
          const int sp = rg0 & 255;
          bf16x4 pk;
          #pragma unroll
          for (int j = 0; j < 4; ++j) pk[j] = (bf16)(acc[m][n][j] + bv);
          *(bf16x4*)(&O1[(((size_t)li * 8 + hh) * 64 + d) * 256 + sp]) = pk;
        }
      }
    }
  }
}

// ---------------------------------------------------------------------------
// Attention per (l,h,s-tile 64). Wave-local softmax: wave wv owns s-rows
// wv*16..+15 x all 256 t (acc = 16 f32x4). K/Q/V read straight from global
// (L2/L3-hot, XCD-grouped siblings share tiles). One barrier (P handoff).
__global__ __launch_bounds__(256, 4) void k_attn(const bf16* __restrict__ Qa,
                                                 const bf16* __restrict__ Ka,
                                                 const bf16* __restrict__ Vt,
                                                 bf16* __restrict__ Oa) {
  __shared__ bf16 Ps[64][264];   // 33792 B; pitch 528B -> 2-way (free) on b128
  __shared__ float rrs[64];      // per-row 1/sum
  const int t = threadIdx.x, wv = t >> 6, ln = t & 63;
  const int q = ln >> 4, r = ln & 15;
  const int bid = blockIdx.x;
  const int st = (bid >> 3) & 3;                 // siblings share bid%8 -> XCD
  const int lh = (bid & 7) | ((bid >> 5) << 3);
  const int s0 = st * 64;
  const size_t base = (size_t)lh * (256 * 64);
  const bf16* Qlh = Qa + base;
  const bf16* Klh = Ka + base;
  const bf16* Vlh = Vt + base;

  // Q A-frags for this wave's 16 rows
  bf16x8 aq[2];
  #pragma unroll
  for (int ks = 0; ks < 2; ++ks)
    aq[ks] = *(const bf16x8*)(Qlh + (size_t)(s0 + wv * 16 + r) * 64 + ks * 32 + q * 8);

  // S = Q K^T ; K B-frags from global
  f32x4 acc[16];
  #pragma unroll
  for (int n = 0; n < 16; ++n) acc[n] = (f32x4){0.f, 0.f, 0.f, 0.f};
  #pragma unroll
  for (int n = 0; n < 16; ++n) {
    const bf16* kb = Klh + (size_t)(n * 16 + r) * 64 + q * 8;
    bf16x8 b0 = *(const bf16x8*)(kb);
    bf16x8 b1 = *(const bf16x8*)(kb + 32);
    acc[n] = MFMA(aq[0], b0, acc[n]);
    acc[n] = MFMA(aq[1], b1, acc[n]);
  }

  // wave-local softmax over t (rows q*4+j): in-lane over n, butterfly over r
  const float SC = 0.125f * 1.4426950408889634f;
  float rs4[4];
  #pragma unroll
  for (int j = 0; j < 4; ++j) {
    float mx = acc[0][j];
    #pragma unroll
    for (int n = 1; n < 16; ++n) mx = fmaxf(mx, acc[n][j]);
    #pragma unroll
    for (int off = 1; off < 16; off <<= 1) mx = fmaxf(mx, __shfl_xor(mx, off));
    const float ms = mx * SC;
    float sm = 0.f;
    #pragma unroll
    for (int n = 0; n < 16; ++n) {
      float p = exp2f(acc[n][j] * SC - ms);
      acc[n][j] = p;
      sm += p;
    }
    #pragma unroll
    for (int off = 1; off < 16; off <<= 1) sm += __shfl_xor(sm, off);
    rs4[j] = 1.f / sm;
    const int row = wv * 16 + q * 4 + j;
    #pragma unroll
    for (int n = 0; n < 16; ++n) Ps[row][n * 16 + r] = (bf16)acc[n][j];
  }
  if (r == 0) *(f32x4*)(&rrs[wv * 16 + q * 4]) = (f32x4){rs4[0], rs4[1], rs4[2], rs4[3]};
  __syncthreads();

  // O = P V : wave wv owns d-cols wv*16..+15, all 64 s-rows
  f32x4 ao[4] = {};
  #pragma unroll
  for (int ks = 0; ks < 8; ++ks) {
    bf16x8 bv = *(const bf16x8*)(Vlh + (size_t)(wv * 16 + r) * 256 + ks * 32 + q * 8);
    #pragma unroll
    for (int m = 0; m < 4; ++m) {
      bf16x8 ap = *(const bf16x8*)(&Ps[m * 16 + r][ks * 32 + q * 8]);
      ao[m] = MFMA(ap, bv, ao[m]);
    }
  }
  #pragma unroll
  for (int m = 0; m < 4; ++m) {
    #pragma unroll
    for (int j = 0; j < 4; ++j) {
      const int row = m * 16 + q * 4 + j;
      float v = ao[m][j] * rrs[row];
      Oa[((size_t)(lh >> 3) * 256 + s0 + row) * 512 + (lh & 7) * 64 + wv * 16 + r] =
          (bf16)v;
    }
  }
}

// ---------------------------------------------------------------------------
// o_tmp[(l*256+s)*512 + e] bf16 -> out[e][Y][X] fp32
__global__ void k_orelay(const bf16* __restrict__ o_tmp, float* __restrict__ out) {
  __shared__ bf16 buf[64][130];
  const int hy = blockIdx.x, py = blockIdx.y, e0 = blockIdx.z * 64, t = threadIdx.x;
  #pragma unroll
  for (int i = 0; i < 32; ++i) {
    int flat = i * 256 + t;
    int r = flat >> 6, e = flat & 63;
    int px = r >> 4, hx = r & 15;
    buf[e][hx * 8 + px] =
        o_tmp[((size_t)(py * 8 + px) * 256 + hy * 16 + hx) * 512 + e0 + e];
  }
  __syncthreads();
  const int Y = hy * 8 + py;
  #pragma unroll
  for (int i = 0; i < 32; ++i) {
    int flat = i * 256 + t;
    int e = flat >> 7, X = flat & 127;
    out[(size_t)(e0 + e) * 16384 + (size_t)Y * 128 + X] = (float)buf[e][X];
  }
}

// ---------------------------------------------------------------------------
extern "C" void kernel_launch(void* const* d_in, const int* in_sizes, int n_in,
                              void* d_out, int out_size, void* d_ws, size_t ws_size,
                              hipStream_t stream) {
  const float* x     = (const float*)d_in[0];
  const float* ln_w  = (const float*)d_in[1];
  const float* ln_b  = (const float*)d_in[2];
  const float* mix_w = (const float*)d_in[3];
  const float* mix_b = (const float*)d_in[4];
  const float* in_w  = (const float*)d_in[5];
  const float* in_b  = (const float*)d_in[6];
  const float* out_w = (const float*)d_in[7];
  const float* out_b = (const float*)d_in[8];
  float* out = (float*)d_out;
  char* ws = (char*)d_ws;

  const size_t MB = 1u << 20;
  float* xp2t = (float*)(ws);                    // [0,8)   pq -> ln
  bf16* qb    = (bf16*)(ws + 8 * MB);            // [8,24)  pq -> gemm0
  bf16* Tn    = (bf16*)(ws + 24 * MB);           // [24,40) ln -> mix
  bf16* ctxb  = (bf16*)(ws + 40 * MB);           // [40,56) mix -> gemm1
  bf16* Qa    = (bf16*)(ws + 56 * MB);           // [56,72) gemm0 -> attn
  bf16* Ka    = (bf16*)(ws);                     // [0,16)  gemm1 -> attn
  bf16* Vt    = (bf16*)(ws + 16 * MB);           // [16,32) gemm1 -> attn
  bf16* oatt  = (bf16*)(ws + 32 * MB);           // [32,48) attn -> gemm2
  bf16* otmp  = (bf16*)(ws + 48 * MB);           // [48,64) gemm2 -> orelay
  bf16* wib   = (bf16*)(ws + 72 * MB);
  bf16* wob   = (bf16*)(ws + 72 * MB + 1572864);

  k_wconv<<<1024, 256, 0, stream>>>(in_w, out_w, wib, wob);
  k_pq<<<dim3(64, 8), 256, 0, stream>>>(x, xp2t, qb);
  k_ln<<<dim3(256, 4), 512, 0, stream>>>(xp2t, ln_w, ln_b, Tn);
  k_mix<<<dim3(256, 2), 256, 0, stream>>>(Tn, mix_w, mix_b, ctxb);
  k_gemm<0><<<dim3(4, 128), 256, 0, stream>>>(qb, wib, in_b, Qa, nullptr);
  k_gemm<1><<<dim3(8, 128), 256, 0, stream>>>(ctxb, wib + 512 * 512, in_b + 512, Ka, Vt);
  k_attn<<<2048, 256, 0, stream>>>(Qa, Ka, Vt, oatt);
  k_gemm<2><<<dim3(4, 128), 256, 0, stream>>>(oatt, wob, out_b, otmp, nullptr);
  k_orelay<<<dim3(16, 8, 8), 256, 0, stream>>>(otmp, out);
}

// Round 4
// 153.424 us; speedup vs baseline: 1.4954x; 1.1057x over previous
//
#include <hip/hip_runtime.h>

// ---------------------------------------------------------------------------
// LargeWindowAttention on MI355X (gfx950)
// pq(fused pool+q-relayout) -> ln -> mix(MFMA) -> QKV GEMMs (bf16 MFMA) ->
// batched window attention (flash 2-half, online softmax) -> out GEMM -> relayout.
// ---------------------------------------------------------------------------

typedef __bf16 bf16;
typedef __bf16 bf16x2 __attribute__((ext_vector_type(2)));
typedef __bf16 bf16x4 __attribute__((ext_vector_type(4)));
typedef __bf16 bf16x8 __attribute__((ext_vector_type(8)));
typedef float f32x4 __attribute__((ext_vector_type(4)));

#define MFMA(a, b, c) __builtin_amdgcn_mfma_f32_16x16x32_bf16(a, b, c, 0, 0, 0)

__device__ __forceinline__ void gll16(const void* g, void* l) {
  __builtin_amdgcn_global_load_lds((const __attribute__((address_space(1))) void*)g,
                                   (__attribute__((address_space(3))) void*)l, 16, 0, 0);
}

// ---------------------------------------------------------------------------
__global__ void k_wconv(const float* __restrict__ in_w, const float* __restrict__ out_w,
                        bf16* __restrict__ wib, bf16* __restrict__ wob) {
  int i = blockIdx.x * blockDim.x + threadIdx.x;
  const int n1 = (1536 * 512) / 4;
  float4 v;
  bf16* dst;
  if (i < n1) { v = ((const float4*)in_w)[i];      dst = wib + (size_t)i * 4; }
  else        { v = ((const float4*)out_w)[i - n1]; dst = wob + (size_t)(i - n1) * 4; }
  dst[0] = (bf16)v.x; dst[1] = (bf16)v.y; dst[2] = (bf16)v.z; dst[3] = (bf16)v.w;
}

// ---------------------------------------------------------------------------
// Fused: read x once -> pooled xp2t[y2][x2][c] fp32 + q relayout bf16.
__global__ __launch_bounds__(256) void k_pq(const float* __restrict__ x,
                                            float* __restrict__ xp2t,
                                            bf16* __restrict__ qb) {
  __shared__ float xs[2][64][133];
  const int y2 = blockIdx.x, c0 = blockIdx.y * 64, t = threadIdx.x;
  #pragma unroll
  for (int it = 0; it < 16; ++it) {
    int flat = it * 256 + t;
    int ci = flat >> 6, rest = flat & 63;
    int yb = rest >> 5, xq = rest & 31;
    float4 v = *(const float4*)(x + (size_t)(c0 + ci) * 16384 +
                                (size_t)(2 * y2 + yb) * 128 + xq * 4);
    float* d = &xs[yb][ci][xq * 4];
    d[0] = v.x; d[1] = v.y; d[2] = v.z; d[3] = v.w;
  }
  __syncthreads();
  #pragma unroll
  for (int it = 0; it < 16; ++it) {
    int flat = it * 256 + t;
    int x2 = flat >> 6, ci = flat & 63;
    float s = xs[0][ci][2 * x2] + xs[0][ci][2 * x2 + 1] +
              xs[1][ci][2 * x2] + xs[1][ci][2 * x2 + 1];
    xp2t[(size_t)(y2 * 64 + x2) * 512 + c0 + ci] = 0.25f * s;
  }
  #pragma unroll
  for (int yb = 0; yb < 2; ++yb) {
    const int Y = 2 * y2 + yb;
    const int hy = Y >> 3, py = Y & 7;
    #pragma unroll
    for (int it = 0; it < 32; ++it) {
      int flat = it * 256 + t;
      int X = flat >> 6, ci = flat & 63;
      int l = py * 8 + (X & 7), s = hy * 16 + (X >> 3);
      qb[((size_t)l * 256 + s) * 512 + c0 + ci] = (bf16)xs[yb][ci][X];
    }
  }
}

// ---------------------------------------------------------------------------
__global__ __launch_bounds__(512) void k_ln(const float* __restrict__ xp2t,
                                            const float* __restrict__ lnw,
                                            const float* __restrict__ lnb,
                                            bf16* __restrict__ T) {
  __shared__ bf16 Tt[512][24];
  const int s = blockIdx.x, qt = blockIdx.y;
  const int wy = s >> 4, wx = s & 15;
  const int t = threadIdx.x, wv = t >> 6, ln = t & 63;

  float wl[8], bl[8];
  #pragma unroll
  for (int k = 0; k < 8; ++k) { wl[k] = lnw[k * 64 + ln]; bl[k] = lnb[k * 64 + ln]; }

  float v[2][8], mu_[2], rs_[2];
  #pragma unroll
  for (int p = 0; p < 2; ++p) {
    const int l = qt * 16 + wv * 2 + p;
    const int py = l >> 3, px = l & 7;
    const int y2 = wy * 4 - 2 + py, x2 = wx * 4 - 2 + px;
    const bool inb = (y2 >= 0) && (y2 < 64) && (x2 >= 0) && (x2 < 64);
    const float* src = xp2t + (size_t)(y2 * 64 + x2) * 512;
    float sum = 0.f, ssq = 0.f;
    #pragma unroll
    for (int k = 0; k < 8; ++k) {
      float xv = 0.f;
      if (inb) xv = src[k * 64 + ln];
      v[p][k] = xv; sum += xv; ssq += xv * xv;
    }
    #pragma unroll
    for (int off = 1; off < 64; off <<= 1) {
      sum += __shfl_xor(sum, off);
      ssq += __shfl_xor(ssq, off);
    }
    float mu = sum * (1.f / 512.f);
    mu_[p] = mu;
    rs_[p] = rsqrtf(ssq * (1.f / 512.f) - mu * mu + 1e-6f);
  }
  #pragma unroll
  for (int k = 0; k < 8; ++k) {
    const int c = k * 64 + ln;
    bf16x2 u;
    u.x = (bf16)((v[0][k] - mu_[0]) * rs_[0] * wl[k] + bl[k]);
    u.y = (bf16)((v[1][k] - mu_[1]) * rs_[1] * wl[k] + bl[k]);
    *(bf16x2*)(&Tt[c][wv * 2]) = u;
  }
  __syncthreads();
  #pragma unroll
  for (int it = 0; it < 2; ++it) {
    int flat = it * 512 + t;
    int c = flat >> 1, ch = flat & 1;
    bf16x8 u = *(const bf16x8*)(&Tt[c][ch * 8]);
    *(bf16x8*)(T + ((size_t)s * 512 + c) * 64 + qt * 16 + ch * 8) = u;
  }
}

// ---------------------------------------------------------------------------
__global__ __launch_bounds__(256) void k_mix(const bf16* __restrict__ T,
                                             const float* __restrict__ mix_w,
                                             const float* __restrict__ mix_b,
                                             bf16* __restrict__ ctx) {
  const int t = threadIdx.x, wv = t >> 6, ln = t & 63;
  const int s = blockIdx.x, hg = blockIdx.y;
  const int h = hg * 4 + wv;
  const int q = ln >> 4, r = ln & 15;

  bf16x8 a[4][2];
  #pragma unroll
  for (int m = 0; m < 4; ++m) {
    #pragma unroll
    for (int ks = 0; ks < 2; ++ks) {
      const int rm = m * 16 + r;
      const float* wsrc = mix_w + ((size_t)h * 64 + rm) * 64 + ks * 32 + q * 8;
      bf16x8 pk;
      #pragma unroll
      for (int e = 0; e < 8; ++e) {
        int l = ks * 32 + q * 8 + e;
        float w = wsrc[e] + (rm == l ? 1.f : 0.f);
        pk[e] = (bf16)w;
      }
      a[m][ks] = pk;
    }
  }
  const bf16* Tb = T + ((size_t)s * 512 + h * 64) * 64;
  bf16x8 b[4][2];
  #pragma unroll
  for (int n = 0; n < 4; ++n) {
    #pragma unroll
    for (int ks = 0; ks < 2; ++ks)
      b[n][ks] = *(const bf16x8*)(Tb + (size_t)(n * 16 + r) * 64 + ks * 32 + q * 8);
  }
  f32x4 acc[4][4] = {};
  #pragma unroll
  for (int ks = 0; ks < 2; ++ks) {
    #pragma unroll
    for (int m = 0; m < 4; ++m) {
      #pragma unroll
      for (int n = 0; n < 4; ++n) acc[m][n] = MFMA(a[m][ks], b[n][ks], acc[m][n]);
    }
  }
  #pragma unroll
  for (int m = 0; m < 4; ++m) {
    #pragma unroll
    for (int j = 0; j < 4; ++j) {
      const int rm = m * 16 + q * 4 + j;
      const float bias = mix_b[h * 64 + rm];
      #pragma unroll
      for (int n = 0; n < 4; ++n)
        ctx[((size_t)rm * 256 + s) * 512 + h * 64 + n * 16 + r] =
            (bf16)(acc[m][n][j] + bias);
    }
  }
}

// ---------------------------------------------------------------------------
// GEMM C[M,N] = A[M,K=512] @ B[N,K=512]^T + bias, bf16 in, fp32 accum.
template <int MODE>
__global__ __launch_bounds__(256, 3) void k_gemm(const bf16* __restrict__ A,
                                                 const bf16* __restrict__ B,
                                                 const float* __restrict__ bias,
                                                 bf16* __restrict__ O0,
                                                 bf16* __restrict__ O1) {
  __shared__ bf16 As[4096];
  __shared__ bf16 Bs[4096];
  const int t = threadIdx.x, wv = t >> 6, ln = t & 63;
  const int bm = blockIdx.y, bn = blockIdx.x;
  const int wm = wv >> 1, wn = wv & 1;
  f32x4 acc[4][4] = {};

  const int srow = wv * 32 + (ln >> 2);
  const int scolb = (ln & 3) * 16;
  const char* ga = (const char*)A + ((size_t)(bm * 128 + srow) * 512) * 2 + scolb;
  const char* gb = (const char*)B + ((size_t)(bn * 128 + srow) * 512) * 2 + scolb;
  bf16* lA = As + wv * 1024;
  bf16* lB = Bs + wv * 1024;

  for (int k0 = 0; k0 < 512; k0 += 32) {
    gll16(ga + k0 * 2,             lA);
    gll16(ga + k0 * 2 + 16 * 1024, lA + 512);
    gll16(gb + k0 * 2,             lB);
    gll16(gb + k0 * 2 + 16 * 1024, lB + 512);
    __syncthreads();
    bf16x8 af[4], bfr[4];
    #pragma unroll
    for (int m = 0; m < 4; ++m)
      af[m] = *(const bf16x8*)(As + (wm * 64 + m * 16 + (ln & 15)) * 32 + (ln >> 4) * 8);
    #pragma unroll
    for (int n = 0; n < 4; ++n)
      bfr[n] = *(const bf16x8*)(Bs + (wn * 64 + n * 16 + (ln & 15)) * 32 + (ln >> 4) * 8);
    #pragma unroll
    for (int m = 0; m < 4; ++m) {
      #pragma unroll
      for (int n = 0; n < 4; ++n) acc[m][n] = MFMA(af[m], bfr[n], acc[m][n]);
    }
    __syncthreads();
  }

  const int r0 = bm * 128 + wm * 64 + (ln >> 4) * 4;
  const int c0 = bn * 128 + wn * 64 + (ln & 15);
  #pragma unroll
  for (int m = 0; m < 4; ++m) {
    const int rg0 = r0 + m * 16;
    #pragma unroll
    for (int n = 0; n < 4; ++n) {
      const int cg = c0 + n * 16;
      const float bv = bias[cg];
      if constexpr (MODE == 2) {
        #pragma unroll
        for (int j = 0; j < 4; ++j)
          O0[(size_t)(rg0 + j) * 512 + cg] = (bf16)(acc[m][n][j] + bv);
      } else if constexpr (MODE == 0) {
        const int li = rg0 >> 8;
        #pragma unroll
        for (int j = 0; j < 4; ++j) {
          int sp = (rg0 + j) & 255;
          O0[(((size_t)li * 8 + (cg >> 6)) * 256 + sp) * 64 + (cg & 63)] =
              (bf16)(acc[m][n][j] + bv);
        }
      } else {  // MODE 1
        const int li = rg0 >> 8;
        if (cg < 512) {
          #pragma unroll
          for (int j = 0; j < 4; ++j) {
            int sp = (rg0 + j) & 255;
            O0[(((size_t)li * 8 + (cg >> 6)) * 256 + sp) * 64 + (cg & 63)] =
                (bf16)(acc[m][n][j] + bv);
          }
        } else {
          const int e = cg - 512, hh = e >> 6, d = e & 63;
          const int sp = rg0 & 255;
          bf16x4 pk;
          #pragma unroll
          for (int j = 0; j < 4; ++j) pk[j] = (bf16)(acc[m][n][j] + bv);
          *(bf16x4*)(&O1[(((size_t)li * 8 + hh) * 64 + d) * 256 + sp]) = pk;
        }
      }
    }
  }
}

// ---------------------------------------------------------------------------
// Attention per (l,h,s-tile 64), flash over t in 2 halves of 128.
// Wave wv: QK^T rows wv*16..+15 (acc 8xf32x4), online softmax wave-local;
// PV: wave owns d-cols wv*16..+15 over all 64 rows, rescale between halves.
// K staged in padded LDS (prefetch h1 during softmax h0 / write during PV h0);
// V prefetched to regs under softmax. Epilogue: LDS transpose -> 16B stores.
__global__ __launch_bounds__(256, 4) void k_attn(const bf16* __restrict__ Qa,
                                                 const bf16* __restrict__ Ka,
                                                 const bf16* __restrict__ Vt,
                                                 bf16* __restrict__ Oa) {
  __shared__ bf16 Ks[128][68];   // 17408 B, pitch 136B (dw stride 34 -> ~2-way)
  __shared__ bf16 Ps[64][132];   // 16896 B
  __shared__ float sfl[64];
  __shared__ float rrs[64];

  const int t = threadIdx.x, wv = t >> 6, ln = t & 63;
  const int q = ln >> 4, r = ln & 15;
  const int bid = blockIdx.x;
  const int st = (bid >> 3) & 3;                 // siblings share bid%8 -> XCD
  const int lh = (bid & 7) | ((bid >> 5) << 3);
  const int s0 = st * 64;
  const size_t base = (size_t)lh * (256 * 64);
  const bf16* Qlh = Qa + base;
  const bf16* Klh = Ka + base;
  const bf16* Vlh = Vt + base;

  const float SC = 0.125f * 1.4426950408889634f;

  // Q A-frags (rows s0 + wv*16 + r)
  bf16x8 aq[2];
  #pragma unroll
  for (int ks = 0; ks < 2; ++ks)
    aq[ks] = *(const bf16x8*)(Qlh + (size_t)(s0 + wv * 16 + r) * 64 + ks * 32 + q * 8);

  // stage K half0: thread covers row t>>1, 64B half (t&1)
  const int krow = t >> 1, khf = (t & 1) * 32;
  {
    bf16x8 kst0[4];
    #pragma unroll
    for (int i = 0; i < 4; ++i)
      kst0[i] = *(const bf16x8*)(Klh + (size_t)krow * 64 + khf + i * 8);
    #pragma unroll
    for (int i = 0; i < 4; ++i) *(bf16x8*)(&Ks[krow][khf + i * 8]) = kst0[i];
  }
  __syncthreads();

  f32x4 ao[4] = {};
  float m4[4], l4[4];
  f32x4 acc[8];

  // ================= half 0 =================
  #pragma unroll
  for (int n = 0; n < 8; ++n) acc[n] = (f32x4){0.f, 0.f, 0.f, 0.f};
  #pragma unroll
  for (int n = 0; n < 8; ++n) {
    bf16x8 b0 = *(const bf16x8*)(&Ks[n * 16 + r][q * 8]);
    bf16x8 b1 = *(const bf16x8*)(&Ks[n * 16 + r][32 + q * 8]);
    acc[n] = MFMA(aq[0], b0, acc[n]);
    acc[n] = MFMA(aq[1], b1, acc[n]);
  }

  // prefetch V half0 (regs) + K half1 (regs), latency hidden under softmax
  bf16x8 bv[4];
  #pragma unroll
  for (int ks = 0; ks < 4; ++ks)
    bv[ks] = *(const bf16x8*)(Vlh + (size_t)(wv * 16 + r) * 256 + ks * 32 + q * 8);
  bf16x8 kst[4];
  #pragma unroll
  for (int i = 0; i < 4; ++i)
    kst[i] = *(const bf16x8*)(Klh + (size_t)(128 + krow) * 64 + khf + i * 8);

  // softmax half0 (init running stats)
  #pragma unroll
  for (int j = 0; j < 4; ++j) {
    float mx = acc[0][j];
    #pragma unroll
    for (int n = 1; n < 8; ++n) mx = fmaxf(mx, acc[n][j]);
    #pragma unroll
    for (int off = 1; off < 16; off <<= 1) mx = fmaxf(mx, __shfl_xor(mx, off));
    m4[j] = mx;
    const float ms = mx * SC;
    float sm = 0.f;
    #pragma unroll
    for (int n = 0; n < 8; ++n) {
      float p = exp2f(acc[n][j] * SC - ms);
      acc[n][j] = p;
      sm += p;
    }
    #pragma unroll
    for (int off = 1; off < 16; off <<= 1) sm += __shfl_xor(sm, off);
    l4[j] = sm;
    const int row = wv * 16 + q * 4 + j;
    #pragma unroll
    for (int n = 0; n < 8; ++n) Ps[row][n * 16 + r] = (bf16)acc[n][j];
  }
  __syncthreads();   // Ps0 ready; Ks dead (all waves past QK^T h0)

  // write K half1 into LDS (loads arrived during softmax), then PV half0
  #pragma unroll
  for (int i = 0; i < 4; ++i) *(bf16x8*)(&Ks[krow][khf + i * 8]) = kst[i];
  #pragma unroll
  for (int ks = 0; ks < 4; ++ks) {
    #pragma unroll
    for (int m = 0; m < 4; ++m) {
      bf16x8 ap = *(const bf16x8*)(&Ps[m * 16 + r][ks * 32 + q * 8]);
      ao[m] = MFMA(ap, bv[ks], ao[m]);
    }
  }
  __syncthreads();   // K1 visible; Ps0 consumed

  // ================= half 1 =================
  #pragma unroll
  for (int n = 0; n < 8; ++n) acc[n] = (f32x4){0.f, 0.f, 0.f, 0.f};
  #pragma unroll
  for (int n = 0; n < 8; ++n) {
    bf16x8 b0 = *(const bf16x8*)(&Ks[n * 16 + r][q * 8]);
    bf16x8 b1 = *(const bf16x8*)(&Ks[n * 16 + r][32 + q * 8]);
    acc[n] = MFMA(aq[0], b0, acc[n]);
    acc[n] = MFMA(aq[1], b1, acc[n]);
  }
  // prefetch V half1
  #pragma unroll
  for (int ks = 0; ks < 4; ++ks)
    bv[ks] = *(const bf16x8*)(Vlh + (size_t)(wv * 16 + r) * 256 + 128 + ks * 32 + q * 8);

  // softmax half1 + online merge
  float sf4[4], rr4[4];
  #pragma unroll
  for (int j = 0; j < 4; ++j) {
    float mx = acc[0][j];
    #pragma unroll
    for (int n = 1; n < 8; ++n) mx = fmaxf(mx, acc[n][j]);
    #pragma unroll
    for (int off = 1; off < 16; off <<= 1) mx = fmaxf(mx, __shfl_xor(mx, off));
    const float mn = fmaxf(m4[j], mx);
    const float sf = exp2f((m4[j] - mn) * SC);
    const float ms = mn * SC;
    float sm = 0.f;
    #pragma unroll
    for (int n = 0; n < 8; ++n) {
      float p = exp2f(acc[n][j] * SC - ms);
      acc[n][j] = p;
      sm += p;
    }
    #pragma unroll
    for (int off = 1; off < 16; off <<= 1) sm += __shfl_xor(sm, off);
    sf4[j] = sf;
    rr4[j] = 1.f / (l4[j] * sf + sm);
    const int row = wv * 16 + q * 4 + j;
    #pragma unroll
    for (int n = 0; n < 8; ++n) Ps[row][n * 16 + r] = (bf16)acc[n][j];
  }
  if (r == 0) {
    *(f32x4*)(&sfl[wv * 16 + q * 4]) = (f32x4){sf4[0], sf4[1], sf4[2], sf4[3]};
    *(f32x4*)(&rrs[wv * 16 + q * 4]) = (f32x4){rr4[0], rr4[1], rr4[2], rr4[3]};
  }
  __syncthreads();   // Ps1 + stats ready; Ks dead (QK^T h1 done everywhere)

  // PV half1 with rescale
  #pragma unroll
  for (int m = 0; m < 4; ++m) {
    f32x4 sv = *(const f32x4*)(&sfl[m * 16 + q * 4]);
    #pragma unroll
    for (int j = 0; j < 4; ++j) ao[m][j] *= sv[j];
  }
  #pragma unroll
  for (int ks = 0; ks < 4; ++ks) {
    #pragma unroll
    for (int m = 0; m < 4; ++m) {
      bf16x8 ap = *(const bf16x8*)(&Ps[m * 16 + r][ks * 32 + q * 8]);
      ao[m] = MFMA(ap, bv[ks], ao[m]);
    }
  }

  // scale by 1/l, stash fp32 into FS (aliases dead Ks), transpose-store
  float(*FS)[68] = (float(*)[68])(&Ks[0][0]);   // 64x68 f32 = 17408 B
  #pragma unroll
  for (int m = 0; m < 4; ++m) {
    f32x4 rv = *(const f32x4*)(&rrs[m * 16 + q * 4]);
    #pragma unroll
    for (int j = 0; j < 4; ++j)
      FS[m * 16 + q * 4 + j][wv * 16 + r] = ao[m][j] * rv[j];
  }
  __syncthreads();

  {
    const int row = t >> 2, qq = t & 3;
    const float* srcp = &FS[row][qq * 16];
    bf16x8 o0, o1;
    #pragma unroll
    for (int i = 0; i < 8; ++i) o0[i] = (bf16)srcp[i];
    #pragma unroll
    for (int i = 0; i < 8; ++i) o1[i] = (bf16)srcp[8 + i];
    bf16* dst = Oa + ((size_t)(lh >> 3) * 256 + s0 + row) * 512 + (lh & 7) * 64 + qq * 16;
    *(bf16x8*)(dst) = o0;
    *(bf16x8*)(dst + 8) = o1;
  }
}

// ---------------------------------------------------------------------------
__global__ void k_orelay(const bf16* __restrict__ o_tmp, float* __restrict__ out) {
  __shared__ bf16 buf[64][130];
  const int hy = blockIdx.x, py = blockIdx.y, e0 = blockIdx.z * 64, t = threadIdx.x;
  #pragma unroll
  for (int i = 0; i < 32; ++i) {
    int flat = i * 256 + t;
    int r = flat >> 6, e = flat & 63;
    int px = r >> 4, hx = r & 15;
    buf[e][hx * 8 + px] =
        o_tmp[((size_t)(py * 8 + px) * 256 + hy * 16 + hx) * 512 + e0 + e];
  }
  __syncthreads();
  const int Y = hy * 8 + py;
  #pragma unroll
  for (int i = 0; i < 32; ++i) {
    int flat = i * 256 + t;
    int e = flat >> 7, X = flat & 127;
    out[(size_t)(e0 + e) * 16384 + (size_t)Y * 128 + X] = (float)buf[e][X];
  }
}

// ---------------------------------------------------------------------------
extern "C" void kernel_launch(void* const* d_in, const int* in_sizes, int n_in,
                              void* d_out, int out_size, void* d_ws, size_t ws_size,
                              hipStream_t stream) {
  const float* x     = (const float*)d_in[0];
  const float* ln_w  = (const float*)d_in[1];
  const float* ln_b  = (const float*)d_in[2];
  const float* mix_w = (const float*)d_in[3];
  const float* mix_b = (const float*)d_in[4];
  const float* in_w  = (const float*)d_in[5];
  const float* in_b  = (const float*)d_in[6];
  const float* out_w = (const float*)d_in[7];
  const float* out_b = (const float*)d_in[8];
  float* out = (float*)d_out;
  char* ws = (char*)d_ws;

  const size_t MB = 1u << 20;
  float* xp2t = (float*)(ws);                    // [0,8)   pq -> ln
  bf16* qb    = (bf16*)(ws + 8 * MB);            // [8,24)  pq -> gemm0
  bf16* Tn    = (bf16*)(ws + 24 * MB);           // [24,40) ln -> mix
  bf16* ctxb  = (bf16*)(ws + 40 * MB);           // [40,56) mix -> gemm1
  bf16* Qa    = (bf16*)(ws + 56 * MB);           // [56,72) gemm0 -> attn
  bf16* Ka    = (bf16*)(ws);                     // [0,16)  gemm1 -> attn
  bf16* Vt    = (bf16*)(ws + 16 * MB);           // [16,32) gemm1 -> attn
  bf16* oatt  = (bf16*)(ws + 32 * MB);           // [32,48) attn -> gemm2
  bf16* otmp  = (bf16*)(ws + 48 * MB);           // [48,64) gemm2 -> orelay
  bf16* wib   = (bf16*)(ws + 72 * MB);
  bf16* wob   = (bf16*)(ws + 72 * MB + 1572864);

  k_wconv<<<1024, 256, 0, stream>>>(in_w, out_w, wib, wob);
  k_pq<<<dim3(64, 8), 256, 0, stream>>>(x, xp2t, qb);
  k_ln<<<dim3(256, 4), 512, 0, stream>>>(xp2t, ln_w, ln_b, Tn);
  k_mix<<<dim3(256, 2), 256, 0, stream>>>(Tn, mix_w, mix_b, ctxb);
  k_gemm<0><<<dim3(4, 128), 256, 0, stream>>>(qb, wib, in_b, Qa, nullptr);
  k_gemm<1><<<dim3(8, 128), 256, 0, stream>>>(ctxb, wib + 512 * 512, in_b + 512, Ka, Vt);
  k_attn<<<2048, 256, 0, stream>>>(Qa, Ka, Vt, oatt);
  k_gemm<2><<<dim3(4, 128), 256, 0, stream>>>(oatt, wob, out_b, otmp, nullptr);
  k_orelay<<<dim3(16, 8, 8), 256, 0, stream>>>(otmp, out);
}

// Round 5
// 138.562 us; speedup vs baseline: 1.6558x; 1.1073x over previous
//
#include <hip/hip_runtime.h>

// ---------------------------------------------------------------------------
// LargeWindowAttention on MI355X (gfx950)
// pq(fused pool+q-relayout) -> ln -> mix(MFMA) -> QKV GEMMs (bf16 MFMA) ->
// batched window attention (flash 2-half, online softmax) -> out GEMM -> relayout.
// ---------------------------------------------------------------------------

typedef __bf16 bf16;
typedef __bf16 bf16x2 __attribute__((ext_vector_type(2)));
typedef __bf16 bf16x4 __attribute__((ext_vector_type(4)));
typedef __bf16 bf16x8 __attribute__((ext_vector_type(8)));
typedef float f32x4 __attribute__((ext_vector_type(4)));

#define MFMA(a, b, c) __builtin_amdgcn_mfma_f32_16x16x32_bf16(a, b, c, 0, 0, 0)

__device__ __forceinline__ void gll16(const void* g, void* l) {
  __builtin_amdgcn_global_load_lds((const __attribute__((address_space(1))) void*)g,
                                   (__attribute__((address_space(3))) void*)l, 16, 0, 0);
}

// ---------------------------------------------------------------------------
__global__ void k_wconv(const float* __restrict__ in_w, const float* __restrict__ out_w,
                        bf16* __restrict__ wib, bf16* __restrict__ wob) {
  int i = blockIdx.x * blockDim.x + threadIdx.x;
  const int n1 = (1536 * 512) / 4;
  float4 v;
  bf16* dst;
  if (i < n1) { v = ((const float4*)in_w)[i];      dst = wib + (size_t)i * 4; }
  else        { v = ((const float4*)out_w)[i - n1]; dst = wob + (size_t)(i - n1) * 4; }
  dst[0] = (bf16)v.x; dst[1] = (bf16)v.y; dst[2] = (bf16)v.z; dst[3] = (bf16)v.w;
}

// ---------------------------------------------------------------------------
// Fused: read x once -> pooled xp2t[y2][x2][c] fp32 + q relayout bf16.
__global__ __launch_bounds__(256) void k_pq(const float* __restrict__ x,
                                            float* __restrict__ xp2t,
                                            bf16* __restrict__ qb) {
  __shared__ float xs[2][64][133];
  const int y2 = blockIdx.x, c0 = blockIdx.y * 64, t = threadIdx.x;
  #pragma unroll
  for (int it = 0; it < 16; ++it) {
    int flat = it * 256 + t;
    int ci = flat >> 6, rest = flat & 63;
    int yb = rest >> 5, xq = rest & 31;
    float4 v = *(const float4*)(x + (size_t)(c0 + ci) * 16384 +
                                (size_t)(2 * y2 + yb) * 128 + xq * 4);
    float* d = &xs[yb][ci][xq * 4];
    d[0] = v.x; d[1] = v.y; d[2] = v.z; d[3] = v.w;
  }
  __syncthreads();
  #pragma unroll
  for (int it = 0; it < 16; ++it) {
    int flat = it * 256 + t;
    int x2 = flat >> 6, ci = flat & 63;
    float s = xs[0][ci][2 * x2] + xs[0][ci][2 * x2 + 1] +
              xs[1][ci][2 * x2] + xs[1][ci][2 * x2 + 1];
    xp2t[(size_t)(y2 * 64 + x2) * 512 + c0 + ci] = 0.25f * s;
  }
  #pragma unroll
  for (int yb = 0; yb < 2; ++yb) {
    const int Y = 2 * y2 + yb;
    const int hy = Y >> 3, py = Y & 7;
    #pragma unroll
    for (int it = 0; it < 32; ++it) {
      int flat = it * 256 + t;
      int X = flat >> 6, ci = flat & 63;
      int l = py * 8 + (X & 7), s = hy * 16 + (X >> 3);
      qb[((size_t)l * 256 + s) * 512 + c0 + ci] = (bf16)xs[yb][ci][X];
    }
  }
}

// ---------------------------------------------------------------------------
__global__ __launch_bounds__(512) void k_ln(const float* __restrict__ xp2t,
                                            const float* __restrict__ lnw,
                                            const float* __restrict__ lnb,
                                            bf16* __restrict__ T) {
  __shared__ bf16 Tt[512][24];
  const int s = blockIdx.x, qt = blockIdx.y;
  const int wy = s >> 4, wx = s & 15;
  const int t = threadIdx.x, wv = t >> 6, ln = t & 63;

  float wl[8], bl[8];
  #pragma unroll
  for (int k = 0; k < 8; ++k) { wl[k] = lnw[k * 64 + ln]; bl[k] = lnb[k * 64 + ln]; }

  float v[2][8], mu_[2], rs_[2];
  #pragma unroll
  for (int p = 0; p < 2; ++p) {
    const int l = qt * 16 + wv * 2 + p;
    const int py = l >> 3, px = l & 7;
    const int y2 = wy * 4 - 2 + py, x2 = wx * 4 - 2 + px;
    const bool inb = (y2 >= 0) && (y2 < 64) && (x2 >= 0) && (x2 < 64);
    const float* src = xp2t + (size_t)(y2 * 64 + x2) * 512;
    float sum = 0.f, ssq = 0.f;
    #pragma unroll
    for (int k = 0; k < 8; ++k) {
      float xv = 0.f;
      if (inb) xv = src[k * 64 + ln];
      v[p][k] = xv; sum += xv; ssq += xv * xv;
    }
    #pragma unroll
    for (int off = 1; off < 64; off <<= 1) {
      sum += __shfl_xor(sum, off);
      ssq += __shfl_xor(ssq, off);
    }
    float mu = sum * (1.f / 512.f);
    mu_[p] = mu;
    rs_[p] = rsqrtf(ssq * (1.f / 512.f) - mu * mu + 1e-6f);
  }
  #pragma unroll
  for (int k = 0; k < 8; ++k) {
    const int c = k * 64 + ln;
    bf16x2 u;
    u.x = (bf16)((v[0][k] - mu_[0]) * rs_[0] * wl[k] + bl[k]);
    u.y = (bf16)((v[1][k] - mu_[1]) * rs_[1] * wl[k] + bl[k]);
    *(bf16x2*)(&Tt[c][wv * 2]) = u;
  }
  __syncthreads();
  #pragma unroll
  for (int it = 0; it < 2; ++it) {
    int flat = it * 512 + t;
    int c = flat >> 1, ch = flat & 1;
    bf16x8 u = *(const bf16x8*)(&Tt[c][ch * 8]);
    *(bf16x8*)(T + ((size_t)s * 512 + c) * 64 + qt * 16 + ch * 8) = u;
  }
}

// ---------------------------------------------------------------------------
__global__ __launch_bounds__(256) void k_mix(const bf16* __restrict__ T,
                                             const float* __restrict__ mix_w,
                                             const float* __restrict__ mix_b,
                                             bf16* __restrict__ ctx) {
  const int t = threadIdx.x, wv = t >> 6, ln = t & 63;
  const int s = blockIdx.x, hg = blockIdx.y;
  const int h = hg * 4 + wv;
  const int q = ln >> 4, r = ln & 15;

  bf16x8 a[4][2];
  #pragma unroll
  for (int m = 0; m < 4; ++m) {
    #pragma unroll
    for (int ks = 0; ks < 2; ++ks) {
      const int rm = m * 16 + r;
      const float* wsrc = mix_w + ((size_t)h * 64 + rm) * 64 + ks * 32 + q * 8;
      bf16x8 pk;
      #pragma unroll
      for (int e = 0; e < 8; ++e) {
        int l = ks * 32 + q * 8 + e;
        float w = wsrc[e] + (rm == l ? 1.f : 0.f);
        pk[e] = (bf16)w;
      }
      a[m][ks] = pk;
    }
  }
  const bf16* Tb = T + ((size_t)s * 512 + h * 64) * 64;
  bf16x8 b[4][2];
  #pragma unroll
  for (int n = 0; n < 4; ++n) {
    #pragma unroll
    for (int ks = 0; ks < 2; ++ks)
      b[n][ks] = *(const bf16x8*)(Tb + (size_t)(n * 16 + r) * 64 + ks * 32 + q * 8);
  }
  f32x4 acc[4][4] = {};
  #pragma unroll
  for (int ks = 0; ks < 2; ++ks) {
    #pragma unroll
    for (int m = 0; m < 4; ++m) {
      #pragma unroll
      for (int n = 0; n < 4; ++n) acc[m][n] = MFMA(a[m][ks], b[n][ks], acc[m][n]);
    }
  }
  #pragma unroll
  for (int m = 0; m < 4; ++m) {
    #pragma unroll
    for (int j = 0; j < 4; ++j) {
      const int rm = m * 16 + q * 4 + j;
      const float bias = mix_b[h * 64 + rm];
      #pragma unroll
      for (int n = 0; n < 4; ++n)
        ctx[((size_t)rm * 256 + s) * 512 + h * 64 + n * 16 + r] =
            (bf16)(acc[m][n][j] + bias);
    }
  }
}

// ---------------------------------------------------------------------------
// GEMM C[M,N] = A[M,K=512] @ B[N,K=512]^T + bias, bf16 in, fp32 accum.
// 128x128 tile, BK=64, 4 waves, gll16 staging with XOR-swizzled SOURCE
// (LDS write stays linear; read side applies the same XOR -> ~2-way, free).
// Grid (bm=blockIdx.x, bn=blockIdx.y): bid%8 = bm%8 -> A-panel siblings on
// one XCD (L2 reuse of A).
template <int MODE>
__global__ __launch_bounds__(256, 4) void k_gemm(const bf16* __restrict__ A,
                                                 const bf16* __restrict__ B,
                                                 const float* __restrict__ bias,
                                                 bf16* __restrict__ O0,
                                                 bf16* __restrict__ O1) {
  __shared__ bf16 As[8192];   // [128 rows][64 k] bf16, 128 B/row, swizzled
  __shared__ bf16 Bs[8192];
  const int t = threadIdx.x, wv = t >> 6, ln = t & 63;
  const int bm = blockIdx.x, bn = blockIdx.y;
  const int wm = wv >> 1, wn = wv & 1;
  const int q = ln >> 4, r = ln & 15;
  f32x4 acc[4][4] = {};

  // staging: issue i covers rows i*32 + wv*8 + (ln>>3); 16B col-block ln&7,
  // source pre-swizzled by XOR with row&7 (= ln>>3, per-lane constant).
  const int srow = wv * 8 + (ln >> 3);
  const int swzc = (ln & 7) ^ (ln >> 3);
  const char* ga = (const char*)A + ((size_t)(bm * 128 + srow) * 512) * 2 + swzc * 16;
  const char* gb = (const char*)B + ((size_t)(bn * 128 + srow) * 512) * 2 + swzc * 16;

  for (int k0 = 0; k0 < 512; k0 += 64) {
    #pragma unroll
    for (int i = 0; i < 4; ++i) {
      gll16(ga + (size_t)i * 32 * 1024 + k0 * 2, As + i * 2048 + wv * 512);
      gll16(gb + (size_t)i * 32 * 1024 + k0 * 2, Bs + i * 2048 + wv * 512);
    }
    __syncthreads();
    #pragma unroll
    for (int ks = 0; ks < 2; ++ks) {
      bf16x8 af[4], bfr[4];
      #pragma unroll
      for (int m = 0; m < 4; ++m)
        af[m] = *(const bf16x8*)(As + (wm * 64 + m * 16 + r) * 64 +
                                 (((ks * 4 + q) ^ (r & 7)) * 8));
      #pragma unroll
      for (int n = 0; n < 4; ++n)
        bfr[n] = *(const bf16x8*)(Bs + (wn * 64 + n * 16 + r) * 64 +
                                  (((ks * 4 + q) ^ (r & 7)) * 8));
      #pragma unroll
      for (int m = 0; m < 4; ++m) {
        #pragma unroll
        for (int n = 0; n < 4; ++n) acc[m][n] = MFMA(af[m], bfr[n], acc[m][n]);
      }
    }
    __syncthreads();
  }

  const int r0 = bm * 128 + wm * 64 + q * 4;
  const int c0 = bn * 128 + wn * 64 + r;
  #pragma unroll
  for (int m = 0; m < 4; ++m) {
    const int rg0 = r0 + m * 16;
    #pragma unroll
    for (int n = 0; n < 4; ++n) {
      const int cg = c0 + n * 16;
      const float bv = bias[cg];
      if constexpr (MODE == 2) {
        #pragma unroll
        for (int j = 0; j < 4; ++j)
          O0[(size_t)(rg0 + j) * 512 + cg] = (bf16)(acc[m][n][j] + bv);
      } else if constexpr (MODE == 0) {
        const int li = rg0 >> 8;
        #pragma unroll
        for (int j = 0; j < 4; ++j) {
          int sp = (rg0 + j) & 255;
          O0[(((size_t)li * 8 + (cg >> 6)) * 256 + sp) * 64 + (cg & 63)] =
              (bf16)(acc[m][n][j] + bv);
        }
      } else {  // MODE 1
        const int li = rg0 >> 8;
        if (cg < 512) {
          #pragma unroll
          for (int j = 0; j < 4; ++j) {
            int sp = (rg0 + j) & 255;
            O0[(((size_t)li * 8 + (cg >> 6)) * 256 + sp) * 64 + (cg & 63)] =
                (bf16)(acc[m][n][j] + bv);
          }
        } else {
          const int e = cg - 512, hh = e >> 6, d = e & 63;
          const int sp = rg0 & 255;
          bf16x4 pk;
          #pragma unroll
          for (int j = 0; j < 4; ++j) pk[j] = (bf16)(acc[m][n][j] + bv);
          *(bf16x4*)(&O1[(((size_t)li * 8 + hh) * 64 + d) * 256 + sp]) = pk;
        }
      }
    }
  }
}

// ---------------------------------------------------------------------------
// Attention per (l,h,s-tile 64), flash over t in 2 halves of 128.
__global__ __launch_bounds__(256, 4) void k_attn(const bf16* __restrict__ Qa,
                                                 const bf16* __restrict__ Ka,
                                                 const bf16* __restrict__ Vt,
                                                 bf16* __restrict__ Oa) {
  __shared__ bf16 Ks[128][68];   // 17408 B, pitch 136B (dw stride 34 -> ~2-way)
  __shared__ bf16 Ps[64][132];   // 16896 B
  __shared__ float sfl[64];
  __shared__ float rrs[64];

  const int t = threadIdx.x, wv = t >> 6, ln = t & 63;
  const int q = ln >> 4, r = ln & 15;
  const int bid = blockIdx.x;
  const int st = (bid >> 3) & 3;                 // siblings share bid%8 -> XCD
  const int lh = (bid & 7) | ((bid >> 5) << 3);
  const int s0 = st * 64;
  const size_t base = (size_t)lh * (256 * 64);
  const bf16* Qlh = Qa + base;
  const bf16* Klh = Ka + base;
  const bf16* Vlh = Vt + base;

  const float SC = 0.125f * 1.4426950408889634f;

  bf16x8 aq[2];
  #pragma unroll
  for (int ks = 0; ks < 2; ++ks)
    aq[ks] = *(const bf16x8*)(Qlh + (size_t)(s0 + wv * 16 + r) * 64 + ks * 32 + q * 8);

  const int krow = t >> 1, khf = (t & 1) * 32;
  {
    bf16x8 kst0[4];
    #pragma unroll
    for (int i = 0; i < 4; ++i)
      kst0[i] = *(const bf16x8*)(Klh + (size_t)krow * 64 + khf + i * 8);
    #pragma unroll
    for (int i = 0; i < 4; ++i) *(bf16x8*)(&Ks[krow][khf + i * 8]) = kst0[i];
  }
  __syncthreads();

  f32x4 ao[4] = {};
  float m4[4], l4[4];
  f32x4 acc[8];

  // ================= half 0 =================
  #pragma unroll
  for (int n = 0; n < 8; ++n) acc[n] = (f32x4){0.f, 0.f, 0.f, 0.f};
  #pragma unroll
  for (int n = 0; n < 8; ++n) {
    bf16x8 b0 = *(const bf16x8*)(&Ks[n * 16 + r][q * 8]);
    bf16x8 b1 = *(const bf16x8*)(&Ks[n * 16 + r][32 + q * 8]);
    acc[n] = MFMA(aq[0], b0, acc[n]);
    acc[n] = MFMA(aq[1], b1, acc[n]);
  }

  bf16x8 bv[4];
  #pragma unroll
  for (int ks = 0; ks < 4; ++ks)
    bv[ks] = *(const bf16x8*)(Vlh + (size_t)(wv * 16 + r) * 256 + ks * 32 + q * 8);
  bf16x8 kst[4];
  #pragma unroll
  for (int i = 0; i < 4; ++i)
    kst[i] = *(const bf16x8*)(Klh + (size_t)(128 + krow) * 64 + khf + i * 8);

  #pragma unroll
  for (int j = 0; j < 4; ++j) {
    float mx = acc[0][j];
    #pragma unroll
    for (int n = 1; n < 8; ++n) mx = fmaxf(mx, acc[n][j]);
    #pragma unroll
    for (int off = 1; off < 16; off <<= 1) mx = fmaxf(mx, __shfl_xor(mx, off));
    m4[j] = mx;
    const float ms = mx * SC;
    float sm = 0.f;
    #pragma unroll
    for (int n = 0; n < 8; ++n) {
      float p = exp2f(acc[n][j] * SC - ms);
      acc[n][j] = p;
      sm += p;
    }
    #pragma unroll
    for (int off = 1; off < 16; off <<= 1) sm += __shfl_xor(sm, off);
    l4[j] = sm;
    const int row = wv * 16 + q * 4 + j;
    #pragma unroll
    for (int n = 0; n < 8; ++n) Ps[row][n * 16 + r] = (bf16)acc[n][j];
  }
  __syncthreads();

  #pragma unroll
  for (int i = 0; i < 4; ++i) *(bf16x8*)(&Ks[krow][khf + i * 8]) = kst[i];
  #pragma unroll
  for (int ks = 0; ks < 4; ++ks) {
    #pragma unroll
    for (int m = 0; m < 4; ++m) {
      bf16x8 ap = *(const bf16x8*)(&Ps[m * 16 + r][ks * 32 + q * 8]);
      ao[m] = MFMA(ap, bv[ks], ao[m]);
    }
  }
  __syncthreads();

  // ================= half 1 =================
  #pragma unroll
  for (int n = 0; n < 8; ++n) acc[n] = (f32x4){0.f, 0.f, 0.f, 0.f};
  #pragma unroll
  for (int n = 0; n < 8; ++n) {
    bf16x8 b0 = *(const bf16x8*)(&Ks[n * 16 + r][q * 8]);
    bf16x8 b1 = *(const bf16x8*)(&Ks[n * 16 + r][32 + q * 8]);
    acc[n] = MFMA(aq[0], b0, acc[n]);
    acc[n] = MFMA(aq[1], b1, acc[n]);
  }
  #pragma unroll
  for (int ks = 0; ks < 4; ++ks)
    bv[ks] = *(const bf16x8*)(Vlh + (size_t)(wv * 16 + r) * 256 + 128 + ks * 32 + q * 8);

  float sf4[4], rr4[4];
  #pragma unroll
  for (int j = 0; j < 4; ++j) {
    float mx = acc[0][j];
    #pragma unroll
    for (int n = 1; n < 8; ++n) mx = fmaxf(mx, acc[n][j]);
    #pragma unroll
    for (int off = 1; off < 16; off <<= 1) mx = fmaxf(mx, __shfl_xor(mx, off));
    const float mn = fmaxf(m4[j], mx);
    const float sf = exp2f((m4[j] - mn) * SC);
    const float ms = mn * SC;
    float sm = 0.f;
    #pragma unroll
    for (int n = 0; n < 8; ++n) {
      float p = exp2f(acc[n][j] * SC - ms);
      acc[n][j] = p;
      sm += p;
    }
    #pragma unroll
    for (int off = 1; off < 16; off <<= 1) sm += __shfl_xor(sm, off);
    sf4[j] = sf;
    rr4[j] = 1.f / (l4[j] * sf + sm);
    const int row = wv * 16 + q * 4 + j;
    #pragma unroll
    for (int n = 0; n < 8; ++n) Ps[row][n * 16 + r] = (bf16)acc[n][j];
  }
  if (r == 0) {
    *(f32x4*)(&sfl[wv * 16 + q * 4]) = (f32x4){sf4[0], sf4[1], sf4[2], sf4[3]};
    *(f32x4*)(&rrs[wv * 16 + q * 4]) = (f32x4){rr4[0], rr4[1], rr4[2], rr4[3]};
  }
  __syncthreads();

  #pragma unroll
  for (int m = 0; m < 4; ++m) {
    f32x4 sv = *(const f32x4*)(&sfl[m * 16 + q * 4]);
    #pragma unroll
    for (int j = 0; j < 4; ++j) ao[m][j] *= sv[j];
  }
  #pragma unroll
  for (int ks = 0; ks < 4; ++ks) {
    #pragma unroll
    for (int m = 0; m < 4; ++m) {
      bf16x8 ap = *(const bf16x8*)(&Ps[m * 16 + r][ks * 32 + q * 8]);
      ao[m] = MFMA(ap, bv[ks], ao[m]);
    }
  }

  float(*FS)[68] = (float(*)[68])(&Ks[0][0]);
  #pragma unroll
  for (int m = 0; m < 4; ++m) {
    f32x4 rv = *(const f32x4*)(&rrs[m * 16 + q * 4]);
    #pragma unroll
    for (int j = 0; j < 4; ++j)
      FS[m * 16 + q * 4 + j][wv * 16 + r] = ao[m][j] * rv[j];
  }
  __syncthreads();

  {
    const int row = t >> 2, qq = t & 3;
    const float* srcp = &FS[row][qq * 16];
    bf16x8 o0, o1;
    #pragma unroll
    for (int i = 0; i < 8; ++i) o0[i] = (bf16)srcp[i];
    #pragma unroll
    for (int i = 0; i < 8; ++i) o1[i] = (bf16)srcp[8 + i];
    bf16* dst = Oa + ((size_t)(lh >> 3) * 256 + s0 + row) * 512 + (lh & 7) * 64 + qq * 16;
    *(bf16x8*)(dst) = o0;
    *(bf16x8*)(dst + 8) = o1;
  }
}

// ---------------------------------------------------------------------------
__global__ void k_orelay(const bf16* __restrict__ o_tmp, float* __restrict__ out) {
  __shared__ bf16 buf[64][130];
  const int hy = blockIdx.x, py = blockIdx.y, e0 = blockIdx.z * 64, t = threadIdx.x;
  #pragma unroll
  for (int i = 0; i < 32; ++i) {
    int flat = i * 256 + t;
    int r = flat >> 6, e = flat & 63;
    int px = r >> 4, hx = r & 15;
    buf[e][hx * 8 + px] =
        o_tmp[((size_t)(py * 8 + px) * 256 + hy * 16 + hx) * 512 + e0 + e];
  }
  __syncthreads();
  const int Y = hy * 8 + py;
  #pragma unroll
  for (int i = 0; i < 32; ++i) {
    int flat = i * 256 + t;
    int e = flat >> 7, X = flat & 127;
    out[(size_t)(e0 + e) * 16384 + (size_t)Y * 128 + X] = (float)buf[e][X];
  }
}

// ---------------------------------------------------------------------------
extern "C" void kernel_launch(void* const* d_in, const int* in_sizes, int n_in,
                              void* d_out, int out_size, void* d_ws, size_t ws_size,
                              hipStream_t stream) {
  const float* x     = (const float*)d_in[0];
  const float* ln_w  = (const float*)d_in[1];
  const float* ln_b  = (const float*)d_in[2];
  const float* mix_w = (const float*)d_in[3];
  const float* mix_b = (const float*)d_in[4];
  const float* in_w  = (const float*)d_in[5];
  const float* in_b  = (const float*)d_in[6];
  const float* out_w = (const float*)d_in[7];
  const float* out_b = (const float*)d_in[8];
  float* out = (float*)d_out;
  char* ws = (char*)d_ws;

  const size_t MB = 1u << 20;
  float* xp2t = (float*)(ws);                    // [0,8)   pq -> ln
  bf16* qb    = (bf16*)(ws + 8 * MB);            // [8,24)  pq -> gemm0
  bf16* Tn    = (bf16*)(ws + 24 * MB);           // [24,40) ln -> mix
  bf16* ctxb  = (bf16*)(ws + 40 * MB);           // [40,56) mix -> gemm1
  bf16* Qa    = (bf16*)(ws + 56 * MB);           // [56,72) gemm0 -> attn
  bf16* Ka    = (bf16*)(ws);                     // [0,16)  gemm1 -> attn
  bf16* Vt    = (bf16*)(ws + 16 * MB);           // [16,32) gemm1 -> attn
  bf16* oatt  = (bf16*)(ws + 32 * MB);           // [32,48) attn -> gemm2
  bf16* otmp  = (bf16*)(ws + 48 * MB);           // [48,64) gemm2 -> orelay
  bf16* wib   = (bf16*)(ws + 72 * MB);
  bf16* wob   = (bf16*)(ws + 72 * MB + 1572864);

  k_wconv<<<1024, 256, 0, stream>>>(in_w, out_w, wib, wob);
  k_pq<<<dim3(64, 8), 256, 0, stream>>>(x, xp2t, qb);
  k_ln<<<dim3(256, 4), 512, 0, stream>>>(xp2t, ln_w, ln_b, Tn);
  k_mix<<<dim3(256, 2), 256, 0, stream>>>(Tn, mix_w, mix_b, ctxb);
  k_gemm<0><<<dim3(128, 4), 256, 0, stream>>>(qb, wib, in_b, Qa, nullptr);
  k_gemm<1><<<dim3(128, 8), 256, 0, stream>>>(ctxb, wib + 512 * 512, in_b + 512, Ka, Vt);
  k_attn<<<2048, 256, 0, stream>>>(Qa, Ka, Vt, oatt);
  k_gemm<2><<<dim3(128, 4), 256, 0, stream>>>(oatt, wob, out_b, otmp, nullptr);
  k_orelay<<<dim3(16, 8, 8), 256, 0, stream>>>(otmp, out);
}